// Round 6
// baseline (234.149 us; speedup 1.0000x reference)
//
#include <hip/hip_runtime.h>
#include <hip/hip_bf16.h>
#include <math.h>

typedef __bf16 bf16_t;
typedef __attribute__((ext_vector_type(8))) __bf16 bf16x8;
typedef __attribute__((ext_vector_type(4))) __bf16 bf16x4;
typedef __attribute__((ext_vector_type(4))) float f32x4;

#define BATCH 8
#define NTOK 1024
#define NEDGE 16384
#define CAP 96   // max neighbors per row (deg ~ Poisson(32); P(deg>96) < 1e-20)

// ---------------- async global->LDS (16B per lane, wave-uniform LDS base) ----------------
__device__ __forceinline__ void gload_lds16(const void* g, void* l) {
  __builtin_amdgcn_global_load_lds(
      (const __attribute__((address_space(1))) unsigned int*)(uintptr_t)g,
      (__attribute__((address_space(3))) unsigned int*)(unsigned int)(uintptr_t)l,
      16, 0, 0);
}

// ---------------- fused: zero prio (blocks 0..2047) + f32->bf16 cvt (blocks 2048..5631) ----------------
__global__ void k_pre(int4* __restrict__ prio,
                      const float* __restrict__ H, const float* __restrict__ Wqkv,
                      const float* __restrict__ Wo, const float* __restrict__ W1,
                      const float* __restrict__ W2, bf16_t* __restrict__ xb,
                      bf16_t* __restrict__ wqkvb, bf16_t* __restrict__ wob,
                      bf16_t* __restrict__ w1b, bf16_t* __restrict__ w2b) {
  if (blockIdx.x < 2048) {
    int i = blockIdx.x * 256 + threadIdx.x;
    int4 z = {0, 0, 0, 0};
#pragma unroll
    for (int u = 0; u < 4; ++u) prio[i + u * 524288] = z;   // 4 x 524288 int4 = 32MB
    return;
  }
  int i = (blockIdx.x - 2048) * 256 + threadIdx.x;   // float4-quad index
  const float* s; bf16_t* d; int off;
  if (i < 524288)      { s = H;    d = xb;    off = i; }
  else if (i < 622592) { s = Wqkv; d = wqkvb; off = i - 524288; }
  else if (i < 655360) { s = Wo;   d = wob;   off = i - 622592; }
  else if (i < 786432) { s = W1;   d = w1b;   off = i - 655360; }
  else if (i < 917504) { s = W2;   d = w2b;   off = i - 786432; }
  else return;
  float4 v = ((const float4*)s)[off];
  bf16x4 o;
  o[0] = (bf16_t)v.x; o[1] = (bf16_t)v.y; o[2] = (bf16_t)v.z; o[3] = (bf16_t)v.w;
  ((bf16x4*)d)[off] = o;
}

// ---------------- bias scatter: priority = scatter order (last write wins) ----------------
__global__ void k_scatter(const int* __restrict__ ei, int* __restrict__ prio) {
  int idx = blockIdx.x * 256 + threadIdx.x;
  if (idx >= BATCH * NEDGE) return;
  int b = idx >> 14;
  int e = idx & (NEDGE - 1);
  const int* eb = ei + (size_t)b * 2 * NEDGE;
  int r = eb[e], c = eb[NEDGE + e];
  int base = b << 20;
  atomicMax(prio + base + (r << 10) + c, e + 1);           // first scatter set
  atomicMax(prio + base + (c << 10) + r, NEDGE + e + 1);   // second scatter set (wins)
}

// ---------------- CSR build: one wave per row, deterministic ballot compaction ----------------
__global__ __launch_bounds__(256) void k_build_csr(
    const int* __restrict__ prio, const float* __restrict__ mptr,
    int* __restrict__ nbcol, float* __restrict__ nbval, int* __restrict__ nbcnt) {
  int row = blockIdx.x * 4 + (threadIdx.x >> 6);   // b*1024 + i
  int l = threadIdx.x & 63;
  int i = row & 1023;
  int b = row >> 10;
  int base = 0;
  for (int it = 0; it < 16; ++it) {
    int j = it * 64 + l;
    int p = prio[((size_t)row << 10) + j];
    bool hit = (p > 0) || (j == i);
    unsigned long long mask = __ballot(hit);
    int pos = base + __popcll(mask & ((1ull << l) - 1ull));
    if (hit && pos < CAP) {
      float v = 0.f;
      if (p > 0) {
        int e = (p - 1) & (NEDGE - 1);
        v = logf(mptr[(size_t)b * NEDGE + e] + 1e-9f);
      }
      nbcol[(size_t)row * CAP + pos] = j;
      nbval[(size_t)row * CAP + pos] = v;
    }
    base += __popcll(mask);
  }
  if (l == 0) nbcnt[row] = min(base, CAP);
}

// ---------------- GEMM 128x128, double-buffered LDS + counted vmcnt ----------------
// EPI 1: gelu -> bf16 out. EPI 3: plain bf16 out.
template <int EPI>
__global__ __launch_bounds__(256) void gemm_bt(
    const bf16_t* __restrict__ A, const bf16_t* __restrict__ Bw,
    const float* __restrict__ bias, bf16_t* __restrict__ Cb,
    int M, int N, int K) {
  __shared__ bf16_t As[2][128 * 64];
  __shared__ bf16_t Bs[2][128 * 64];
  const int t = threadIdx.x;
  const int l = t & 63;
  const int w = t >> 6;
  const int wr = w >> 1, wc = w & 1;
  const int bm = blockIdx.y * 128, bn = blockIdx.x * 128;

  f32x4 acc[4][4] = {};

  auto stage = [&](int buf, int k0) {
#pragma unroll
    for (int i = 0; i < 4; ++i) {
      int idx = i * 2048 + t * 8;
      int row = idx >> 6;
      int col = idx & 63;
      gload_lds16(A + (size_t)(bm + row) * K + (k0 + col), (void*)(&As[buf][0] + i * 2048 + w * 512));
      gload_lds16(Bw + (size_t)(bn + row) * K + (k0 + col), (void*)(&Bs[buf][0] + i * 2048 + w * 512));
    }
  };

  const int nt = K >> 6;
  stage(0, 0);
  for (int kt = 0; kt < nt; ++kt) {
    const int cur = kt & 1;
    if (kt + 1 < nt) {
      stage(cur ^ 1, (kt + 1) << 6);                       // next tile in flight
      asm volatile("s_waitcnt vmcnt(8)" ::: "memory");     // only current tile drained
    } else {
      asm volatile("s_waitcnt vmcnt(0)" ::: "memory");
    }
    __syncthreads();
#pragma unroll
    for (int kk = 0; kk < 2; ++kk) {
      bf16x8 af[4], bfr[4];
#pragma unroll
      for (int mi = 0; mi < 4; ++mi)
        af[mi] = *(const bf16x8*)(&As[cur][0] + (wr * 64 + mi * 16 + (l & 15)) * 64 + kk * 32 + (l >> 4) * 8);
#pragma unroll
      for (int ni = 0; ni < 4; ++ni)
        bfr[ni] = *(const bf16x8*)(&Bs[cur][0] + (wc * 64 + ni * 16 + (l & 15)) * 64 + kk * 32 + (l >> 4) * 8);
#pragma unroll
      for (int mi = 0; mi < 4; ++mi)
#pragma unroll
        for (int ni = 0; ni < 4; ++ni)
          acc[mi][ni] = __builtin_amdgcn_mfma_f32_16x16x32_bf16(af[mi], bfr[ni], acc[mi][ni], 0, 0, 0);
    }
    __syncthreads();
  }

  const int r0 = (l >> 4) * 4;   // C/D: row=(lane>>4)*4+reg, col=lane&15
  const int cc = l & 15;
#pragma unroll
  for (int mi = 0; mi < 4; ++mi) {
#pragma unroll
    for (int ni = 0; ni < 4; ++ni) {
      int col = bn + wc * 64 + ni * 16 + cc;
      float bv = bias[col];
#pragma unroll
      for (int r = 0; r < 4; ++r) {
        int row = bm + wr * 64 + mi * 16 + r0 + r;
        float v = acc[mi][ni][r] + bv;
        if (EPI == 1)
          v = 0.5f * v * (1.f + erff(v * 0.70710678118654752f));   // exact GELU
        Cb[(size_t)row * N + col] = (bf16_t)v;
      }
    }
  }
}

// ---------------- fused GEMM(BM=16, BN=256) + bias + residual + LayerNorm ----------------
// double-buffered; y = LN(resid + A@Bw^T + bias); grid = M/16 = 512 blocks (2/CU).
__global__ __launch_bounds__(256) void gemm_ln(
    const bf16_t* __restrict__ A, const bf16_t* __restrict__ Bw,
    const float* __restrict__ bias, const float* __restrict__ resid,
    const float* __restrict__ lnw, const float* __restrict__ lnb,
    float* __restrict__ xfout, bf16_t* __restrict__ xbout, int K) {
  __shared__ __align__(16) char smem[69632];
  bf16_t* As = (bf16_t*)smem;             // [2][16][64] = 4KB
  bf16_t* Bs = (bf16_t*)(smem + 4096);    // [2][256][64] = 64KB
  float*  E  = (float*)smem;              // epi: [16][258] f32 (aliases, after barrier)
  const int t = threadIdx.x;
  const int l = t & 63;
  const int w = t >> 6;
  const int bm = blockIdx.x * 16;

  f32x4 acc[4] = {};

  auto stage = [&](int buf, int k0) {
    if (w < 2) {   // A tile 16x64: waves 0,1 stage 8 rows each (1 issue)
      int row = w * 8 + (l >> 3), col = (l & 7) * 8;
      gload_lds16(A + (size_t)(bm + row) * K + (k0 + col), (void*)(As + buf * 1024 + w * 512));
    }
#pragma unroll
    for (int i = 0; i < 8; ++i) {   // B tile 256x64: 8 issues per wave
      int rr = (w * 8 + i) * 8 + (l >> 3), col = (l & 7) * 8;
      gload_lds16(Bw + (size_t)rr * K + (k0 + col), (void*)(Bs + buf * 16384 + (w * 8 + i) * 512));
    }
  };

  const int nt = K >> 6;
  stage(0, 0);
  for (int kt = 0; kt < nt; ++kt) {
    const int cur = kt & 1;
    if (kt + 1 < nt) {
      stage(cur ^ 1, (kt + 1) << 6);
      if (w < 2) asm volatile("s_waitcnt vmcnt(9)" ::: "memory");   // 1 A + 8 B in flight
      else       asm volatile("s_waitcnt vmcnt(8)" ::: "memory");   // 8 B in flight
    } else {
      asm volatile("s_waitcnt vmcnt(0)" ::: "memory");
    }
    __syncthreads();
#pragma unroll
    for (int kk = 0; kk < 2; ++kk) {
      bf16x8 af = *(const bf16x8*)(As + cur * 1024 + (l & 15) * 64 + kk * 32 + (l >> 4) * 8);
#pragma unroll
      for (int ni = 0; ni < 4; ++ni) {
        bf16x8 bfr = *(const bf16x8*)(Bs + cur * 16384 + (w * 64 + ni * 16 + (l & 15)) * 64 + kk * 32 + (l >> 4) * 8);
        acc[ni] = __builtin_amdgcn_mfma_f32_16x16x32_bf16(af, bfr, acc[ni], 0, 0, 0);
      }
    }
    __syncthreads();
  }

  // stash C+bias into LDS f32 [16][258]
  const int r0 = (l >> 4) * 4;
  const int cc = l & 15;
#pragma unroll
  for (int ni = 0; ni < 4; ++ni) {
    int col = w * 64 + ni * 16 + cc;
    float bv = bias[col];
#pragma unroll
    for (int r = 0; r < 4; ++r)
      E[(r0 + r) * 258 + col] = acc[ni][r] + bv;
  }
  __syncthreads();

  // LN: 16 threads per row, 16 cols per thread
  const int row = t >> 4;
  const int sub = t & 15;
  const float* ep = E + row * 258 + sub * 16;
  const float* rp = resid + (size_t)(bm + row) * 256 + sub * 16;
  float v[16];
  float s = 0.f;
#pragma unroll
  for (int j = 0; j < 4; ++j) {
    float4 a4 = ((const float4*)ep)[j];
    float4 b4 = ((const float4*)rp)[j];
    v[j * 4 + 0] = a4.x + b4.x; v[j * 4 + 1] = a4.y + b4.y;
    v[j * 4 + 2] = a4.z + b4.z; v[j * 4 + 3] = a4.w + b4.w;
    s += v[j * 4 + 0] + v[j * 4 + 1] + v[j * 4 + 2] + v[j * 4 + 3];
  }
#pragma unroll
  for (int o = 1; o < 16; o <<= 1) s += __shfl_xor(s, o);
  float mu = s * (1.f / 256.f);
  float e2 = 0.f;
#pragma unroll
  for (int j = 0; j < 16; ++j) { float d = v[j] - mu; e2 += d * d; }
#pragma unroll
  for (int o = 1; o < 16; o <<= 1) e2 += __shfl_xor(e2, o);
  float rs = rsqrtf(e2 * (1.f / 256.f) + 1e-5f);
  float* xo = xfout + (size_t)(bm + row) * 256 + sub * 16;
  bf16_t* xbo = xbout + (size_t)(bm + row) * 256 + sub * 16;
#pragma unroll
  for (int j = 0; j < 4; ++j) {
    float4 w4 = ((const float4*)(lnw + sub * 16))[j];
    float4 b4 = ((const float4*)(lnb + sub * 16))[j];
    float y0 = (v[j * 4 + 0] - mu) * rs * w4.x + b4.x;
    float y1 = (v[j * 4 + 1] - mu) * rs * w4.y + b4.y;
    float y2 = (v[j * 4 + 2] - mu) * rs * w4.z + b4.z;
    float y3 = (v[j * 4 + 3] - mu) * rs * w4.w + b4.w;
    float4 o4 = {y0, y1, y2, y3};
    ((float4*)xo)[j] = o4;
    bf16x4 ob;
    ob[0] = (bf16_t)y0; ob[1] = (bf16_t)y1; ob[2] = (bf16_t)y2; ob[3] = (bf16_t)y3;
    ((bf16x4*)xbo)[j] = ob;
  }
}

// ---------------- sparse attention: 4 rows/block, one wave per row, all-bf16 qkv ----------------
// qkvb layout: [8192][768] bf16 — q cols 0..255, k 256..511, v 512..767
__global__ __launch_bounds__(256) void k_attn2(
    const bf16_t* __restrict__ qkvb,
    const int* __restrict__ nbcol, const float* __restrict__ nbval,
    const int* __restrict__ nbcnt, bf16_t* __restrict__ aob) {
  const int w = threadIdx.x >> 6;
  const int l = threadIdx.x & 63;
  const int row = blockIdx.x * 4 + w;
  const int b = row >> 10;
  __shared__ float s_s[4][8][97];     // padded: conflict-free ph3
  __shared__ int   s_col[4][CAP];
  __shared__ float s_bias[4][CAP];
  __shared__ float s_den[4][8];
  const int deg = nbcnt[row];
  for (int j = l; j < deg; j += 64) {
    s_col[w][j] = nbcol[(size_t)row * CAP + j];
    s_bias[w][j] = nbval[(size_t)row * CAP + j];
  }
  const int h1 = l & 7;
  float q[32];
  {
    const bf16x8* qp = (const bf16x8*)(qkvb + (size_t)row * 768 + h1 * 32);
#pragma unroll
    for (int u = 0; u < 4; ++u) {
      bf16x8 t8 = qp[u];
#pragma unroll
      for (int j = 0; j < 8; ++j) q[u * 8 + j] = (float)t8[j];
    }
  }
  __syncthreads();

  const float scale = 0.17677669529663687f;   // 1/sqrt(32)
  const int nit = (deg + 7) >> 3;
  // phase 1: scores (8 nbrs x 8 heads per iter)
  float mx = -INFINITY;
  for (int it = 0; it < nit; ++it) {
    int idx = it * 8 + (l >> 3);
    float sc = -INFINITY;
    if (idx < deg) {
      int col = s_col[w][idx];
      const bf16x8* kr = (const bf16x8*)(qkvb + ((size_t)((b << 10) + col)) * 768 + 256 + h1 * 32);
      float d = 0.f;
#pragma unroll
      for (int u = 0; u < 4; ++u) {
        bf16x8 kv = kr[u];
#pragma unroll
        for (int j = 0; j < 8; ++j) d += (float)kv[j] * q[u * 8 + j];
      }
      sc = d * scale + s_bias[w][idx];
      s_s[w][h1][idx] = sc;
    }
    mx = fmaxf(mx, sc);
  }
#pragma unroll
  for (int o = 8; o < 64; o <<= 1) mx = fmaxf(mx, __shfl_xor(mx, o));
  __syncthreads();
  // phase 2: exp + denom
  float lsum = 0.f;
  for (int it = 0; it < nit; ++it) {
    int idx = it * 8 + (l >> 3);
    if (idx < deg) {
      float p = __expf(s_s[w][h1][idx] - mx);
      s_s[w][h1][idx] = p;
      lsum += p;
    }
  }
#pragma unroll
  for (int o = 8; o < 64; o <<= 1) lsum += __shfl_xor(lsum, o);
  if (l < 8) s_den[w][l] = lsum;
  __syncthreads();
  // phase 3: PV — all 64 lanes read one full V row per neighbor
  const int h3 = l >> 3;
  float a0 = 0.f, a1 = 0.f, a2 = 0.f, a3 = 0.f;
  const bf16_t* vbase = qkvb + ((size_t)(b << 10)) * 768 + 512 + l * 4;
#pragma unroll 4
  for (int idx = 0; idx < deg; ++idx) {
    float p = s_s[w][h3][idx];
    bf16x4 vv = *(const bf16x4*)(vbase + (size_t)s_col[w][idx] * 768);
    a0 += p * (float)vv[0]; a1 += p * (float)vv[1];
    a2 += p * (float)vv[2]; a3 += p * (float)vv[3];
  }
  float rden = 1.f / s_den[w][h3];
  bf16x4 o;
  o[0] = (bf16_t)(a0 * rden); o[1] = (bf16_t)(a1 * rden);
  o[2] = (bf16_t)(a2 * rden); o[3] = (bf16_t)(a3 * rden);
  *(bf16x4*)(aob + (size_t)row * 256 + l * 4) = o;
}

// ---------------- final LayerNorm (no residual), wave per row ----------------
__global__ __launch_bounds__(256) void k_ln(
    const float* __restrict__ xin,
    const float* __restrict__ w, const float* __restrict__ b,
    float* __restrict__ xout) {
  int r = blockIdx.x * 4 + (threadIdx.x >> 6);
  int l = threadIdx.x & 63;
  float4 v = ((const float4*)(xin + (size_t)r * 256))[l];
  float s = v.x + v.y + v.z + v.w;
#pragma unroll
  for (int o = 32; o; o >>= 1) s += __shfl_xor(s, o);
  float mu = s * (1.f / 256.f);
  float dx = v.x - mu, dy = v.y - mu, dz = v.z - mu, dw = v.w - mu;
  float e = dx * dx + dy * dy + dz * dz + dw * dw;
#pragma unroll
  for (int o = 32; o; o >>= 1) e += __shfl_xor(e, o);
  float rs = rsqrtf(e * (1.f / 256.f) + 1e-5f);
  float4 wv = ((const float4*)w)[l];
  float4 bv = ((const float4*)b)[l];
  float4 o4 = {dx * rs * wv.x + bv.x, dy * rs * wv.y + bv.y,
               dz * rs * wv.z + bv.z, dw * rs * wv.w + bv.w};
  ((float4*)(xout + (size_t)r * 256))[l] = o4;
}

extern "C" void kernel_launch(void* const* d_in, const int* in_sizes, int n_in,
                              void* d_out, int out_size, void* d_ws, size_t ws_size,
                              hipStream_t stream) {
  const float* H    = (const float*)d_in[0];
  const int*   ei   = (const int*)d_in[1];
  const float* m    = (const float*)d_in[2];
  const float* Wqkv = (const float*)d_in[3];
  const float* bqkv = (const float*)d_in[4];
  const float* Wo   = (const float*)d_in[5];
  const float* bo   = (const float*)d_in[6];
  const float* ln1w = (const float*)d_in[7];
  const float* ln1b = (const float*)d_in[8];
  const float* W1   = (const float*)d_in[9];
  const float* b1   = (const float*)d_in[10];
  const float* W2   = (const float*)d_in[11];
  const float* b2   = (const float*)d_in[12];
  const float* ln2w = (const float*)d_in[13];
  const float* ln2b = (const float*)d_in[14];
  const float* lnfw = (const float*)d_in[15];
  const float* lnfb = (const float*)d_in[16];

  char* ws = (char*)d_ws;
  size_t off = 0;
  auto alloc = [&](size_t bytes) {
    void* p = ws + off;
    off += (bytes + 255) & ~(size_t)255;
    return p;
  };

  // prio (32MB) reused later as qkvb (12MB): prio dead after k_build_csr
  int*    prio  = (int*)alloc((size_t)BATCH * NTOK * NTOK * 4);
  bf16_t* qkvb  = (bf16_t*)prio;                 // [8192][768] bf16
  int*    nbcol = (int*)alloc((size_t)BATCH * NTOK * CAP * 4);
  float*  nbval = (float*)alloc((size_t)BATCH * NTOK * CAP * 4);
  int*    nbcnt = (int*)alloc((size_t)BATCH * NTOK * 4);
  bf16_t* wqkvb = (bf16_t*)alloc((size_t)2 * 768 * 256 * 2);
  bf16_t* wob   = (bf16_t*)alloc((size_t)2 * 256 * 256 * 2);
  bf16_t* w1b   = (bf16_t*)alloc((size_t)2 * 1024 * 256 * 2);
  bf16_t* w2b   = (bf16_t*)alloc((size_t)2 * 256 * 1024 * 2);
  bf16_t* xb    = (bf16_t*)alloc((size_t)8192 * 256 * 2);
  bf16_t* aob   = (bf16_t*)alloc((size_t)8192 * 256 * 2);
  bf16_t* ffb   = (bf16_t*)alloc((size_t)8192 * 1024 * 2);
  float*  xfA   = (float*)alloc((size_t)8192 * 256 * 4);
  float*  xfB   = (float*)alloc((size_t)8192 * 256 * 4);

  k_pre<<<5632, 256, 0, stream>>>((int4*)prio, H, Wqkv, Wo, W1, W2,
                                  xb, wqkvb, wob, w1b, w2b);
  k_scatter<<<(BATCH * NEDGE + 255) / 256, 256, 0, stream>>>(ei, prio);
  k_build_csr<<<BATCH * NTOK / 4, 256, 0, stream>>>(prio, m, nbcol, nbval, nbcnt);

  const float* r1[2] = {H, xfB};    // residual input to ln1 per layer
  for (int lyr = 0; lyr < 2; ++lyr) {
    gemm_bt<3><<<dim3(768 / 128, 8192 / 128), 256, 0, stream>>>(
        xb, wqkvb + (size_t)lyr * 768 * 256, bqkv + lyr * 768, qkvb, 8192, 768, 256);
    k_attn2<<<BATCH * NTOK / 4, 256, 0, stream>>>(qkvb, nbcol, nbval, nbcnt, aob);
    gemm_ln<<<512, 256, 0, stream>>>(
        aob, wob + (size_t)lyr * 256 * 256, bo + lyr * 256, r1[lyr],
        ln1w + lyr * 256, ln1b + lyr * 256, xfA, xb, 256);
    gemm_bt<1><<<dim3(1024 / 128, 8192 / 128), 256, 0, stream>>>(
        xb, w1b + (size_t)lyr * 1024 * 256, b1 + lyr * 1024, ffb, 8192, 1024, 256);
    gemm_ln<<<512, 256, 0, stream>>>(
        ffb, w2b + (size_t)lyr * 256 * 1024, b2 + lyr * 256, xfA,
        ln2w + lyr * 256, ln2b + lyr * 256, xfB, xb, 1024);
  }
  k_ln<<<8192 / 4, 256, 0, stream>>>(xfB, lnfw, lnfb, (float*)d_out);
}

// Round 7
// 230.396 us; speedup vs baseline: 1.0163x; 1.0163x over previous
//
#include <hip/hip_runtime.h>
#include <hip/hip_bf16.h>
#include <math.h>

typedef __bf16 bf16_t;
typedef __attribute__((ext_vector_type(8))) __bf16 bf16x8;
typedef __attribute__((ext_vector_type(4))) __bf16 bf16x4;
typedef __attribute__((ext_vector_type(4))) float f32x4;

#define BATCH 8
#define NTOK 1024
#define NEDGE 16384
#define CAP 96   // max entries per row (deg ~ Poisson(32); P(deg>96) < 1e-20)

// ---------------- async global->LDS (16B per lane, wave-uniform LDS base) ----------------
__device__ __forceinline__ void gload_lds16(const void* g, void* l) {
  __builtin_amdgcn_global_load_lds(
      (const __attribute__((address_space(1))) unsigned int*)(uintptr_t)g,
      (__attribute__((address_space(3))) unsigned int*)(unsigned int)(uintptr_t)l,
      16, 0, 0);
}

// ---------------- fused: f32->bf16 cvt for H + weights; blocks <8 also zero cnt ----------------
__global__ void k_pre(int4* __restrict__ cnt,
                      const float* __restrict__ H, const float* __restrict__ Wqkv,
                      const float* __restrict__ Wo, const float* __restrict__ W1,
                      const float* __restrict__ W2, bf16_t* __restrict__ xb,
                      bf16_t* __restrict__ wqkvb, bf16_t* __restrict__ wob,
                      bf16_t* __restrict__ w1b, bf16_t* __restrict__ w2b) {
  int i = blockIdx.x * 256 + threadIdx.x;   // float4-quad index
  if (blockIdx.x < 8) {
    int4 z = {0, 0, 0, 0};
    cnt[i] = z;                             // 8 blocks x 256 x int4 = 8192 ints
  }
  const float* s; bf16_t* d; int off;
  if (i < 524288)      { s = H;    d = xb;    off = i; }
  else if (i < 622592) { s = Wqkv; d = wqkvb; off = i - 524288; }
  else if (i < 655360) { s = Wo;   d = wob;   off = i - 622592; }
  else if (i < 786432) { s = W1;   d = w1b;   off = i - 655360; }
  else if (i < 917504) { s = W2;   d = w2b;   off = i - 786432; }
  else return;
  float4 v = ((const float4*)s)[off];
  bf16x4 o;
  o[0] = (bf16_t)v.x; o[1] = (bf16_t)v.y; o[2] = (bf16_t)v.z; o[3] = (bf16_t)v.w;
  ((bf16x4*)d)[off] = o;
}

// ---------------- edge scatter: packed (prio<<10|col) appended to per-row lists ----------------
// prio: first scatter (bias[r][c]=bv) -> e+1; second (bias[c][r]=bv) -> NEDGE+e+1 (wins).
__global__ void k_scatter2(const int* __restrict__ ei, int* __restrict__ cnt,
                           int* __restrict__ ent) {
  int idx = blockIdx.x * 256 + threadIdx.x;
  if (idx >= BATCH * NEDGE) return;
  int b = idx >> 14;
  int e = idx & (NEDGE - 1);
  const int* eb = ei + (size_t)b * 2 * NEDGE;
  int r = eb[e], c = eb[NEDGE + e];
  int rowr = (b << 10) + r, rowc = (b << 10) + c;
  int q = atomicAdd(cnt + rowr, 1);
  if (q < CAP) ent[rowr * CAP + q] = ((e + 1) << 10) | c;
  q = atomicAdd(cnt + rowc, 1);
  if (q < CAP) ent[rowc * CAP + q] = ((NEDGE + e + 1) << 10) | r;
}

// ---------------- CSR build v2: dedup per row in LDS, canonical ascending-col order ----------------
__global__ __launch_bounds__(256) void k_build2(
    const int* __restrict__ cnt, const int* __restrict__ ent,
    const float* __restrict__ mptr,
    int* __restrict__ nbcol, float* __restrict__ nbval, int* __restrict__ nbcnt) {
  const int w = threadIdx.x >> 6;
  const int l = threadIdx.x & 63;
  const int row = blockIdx.x * 4 + w;   // b*1024 + i
  const int i = row & 1023;
  const int b = row >> 10;
  __shared__ int sE[4][CAP];
  __shared__ int sW[4][CAP];
  const int n = min(cnt[row], CAP);
  for (int j = l; j < n; j += 64) sE[w][j] = ent[(size_t)row * CAP + j];
  __syncthreads();

  // pass 1: winner flags (max packed value per col; prios unique) + diag coverage
  bool dcov_l = false;
  bool win[2] = {false, false};
  int myc[2], myp[2];
#pragma unroll
  for (int s = 0; s < 2; ++s) {
    int k = s * 64 + l;
    if (k < n) {
      int pk = sE[w][k], ck = pk & 1023;
      myc[s] = ck; myp[s] = pk;
      bool wn = true;
      for (int j = 0; j < n; ++j) {
        int pj = sE[w][j];
        if ((pj & 1023) == ck && pj > pk) wn = false;
      }
      win[s] = wn;
      sW[w][k] = wn ? 1 : 0;
      if (ck == i) dcov_l = true;
    }
  }
  const bool dcov = __any(dcov_l);
  unsigned long long m0 = __ballot(win[0]);
  unsigned long long m1 = __ballot(win[1]);
  if (l == 0) nbcnt[row] = __popcll(m0) + __popcll(m1) + (dcov ? 0 : 1);

  // pass 2: position = #winners with smaller col (+ virtual diag if it sorts earlier)
#pragma unroll
  for (int s = 0; s < 2; ++s) {
    int k = s * 64 + l;
    if (k < n && win[s]) {
      int pos = 0;
      for (int j = 0; j < n; ++j)
        if (sW[w][j] && (sE[w][j] & 1023) < myc[s]) ++pos;
      if (!dcov && i < myc[s]) ++pos;
      int e = ((myp[s] >> 10) - 1) & (NEDGE - 1);
      float v = logf(mptr[(size_t)b * NEDGE + e] + 1e-9f);
      if (pos < CAP) {
        nbcol[(size_t)row * CAP + pos] = myc[s];
        nbval[(size_t)row * CAP + pos] = v;
      }
    }
  }
  if (!dcov && l == 0) {   // virtual diagonal (value 0)
    int pos = 0;
    for (int j = 0; j < n; ++j)
      if (sW[w][j] && (sE[w][j] & 1023) < i) ++pos;
    nbcol[(size_t)row * CAP + pos] = i;
    nbval[(size_t)row * CAP + pos] = 0.f;
  }
}

// ---------------- GEMM 128x128, double-buffered LDS + counted vmcnt ----------------
// EPI 1: gelu -> bf16 out. EPI 3: plain bf16 out.
template <int EPI>
__global__ __launch_bounds__(256) void gemm_bt(
    const bf16_t* __restrict__ A, const bf16_t* __restrict__ Bw,
    const float* __restrict__ bias, bf16_t* __restrict__ Cb,
    int M, int N, int K) {
  __shared__ bf16_t As[2][128 * 64];
  __shared__ bf16_t Bs[2][128 * 64];
  const int t = threadIdx.x;
  const int l = t & 63;
  const int w = t >> 6;
  const int wr = w >> 1, wc = w & 1;
  const int bm = blockIdx.y * 128, bn = blockIdx.x * 128;

  f32x4 acc[4][4] = {};

  auto stage = [&](int buf, int k0) {
#pragma unroll
    for (int i = 0; i < 4; ++i) {
      int idx = i * 2048 + t * 8;
      int row = idx >> 6;
      int col = idx & 63;
      gload_lds16(A + (size_t)(bm + row) * K + (k0 + col), (void*)(&As[buf][0] + i * 2048 + w * 512));
      gload_lds16(Bw + (size_t)(bn + row) * K + (k0 + col), (void*)(&Bs[buf][0] + i * 2048 + w * 512));
    }
  };

  const int nt = K >> 6;
  stage(0, 0);
  for (int kt = 0; kt < nt; ++kt) {
    const int cur = kt & 1;
    if (kt + 1 < nt) {
      stage(cur ^ 1, (kt + 1) << 6);
      asm volatile("s_waitcnt vmcnt(8)" ::: "memory");
    } else {
      asm volatile("s_waitcnt vmcnt(0)" ::: "memory");
    }
    __syncthreads();
#pragma unroll
    for (int kk = 0; kk < 2; ++kk) {
      bf16x8 af[4], bfr[4];
#pragma unroll
      for (int mi = 0; mi < 4; ++mi)
        af[mi] = *(const bf16x8*)(&As[cur][0] + (wr * 64 + mi * 16 + (l & 15)) * 64 + kk * 32 + (l >> 4) * 8);
#pragma unroll
      for (int ni = 0; ni < 4; ++ni)
        bfr[ni] = *(const bf16x8*)(&Bs[cur][0] + (wc * 64 + ni * 16 + (l & 15)) * 64 + kk * 32 + (l >> 4) * 8);
#pragma unroll
      for (int mi = 0; mi < 4; ++mi)
#pragma unroll
        for (int ni = 0; ni < 4; ++ni)
          acc[mi][ni] = __builtin_amdgcn_mfma_f32_16x16x32_bf16(af[mi], bfr[ni], acc[mi][ni], 0, 0, 0);
    }
    __syncthreads();
  }

  const int r0 = (l >> 4) * 4;   // C/D: row=(lane>>4)*4+reg, col=lane&15
  const int cc = l & 15;
#pragma unroll
  for (int mi = 0; mi < 4; ++mi) {
#pragma unroll
    for (int ni = 0; ni < 4; ++ni) {
      int col = bn + wc * 64 + ni * 16 + cc;
      float bv = bias[col];
#pragma unroll
      for (int r = 0; r < 4; ++r) {
        int row = bm + wr * 64 + mi * 16 + r0 + r;
        float v = acc[mi][ni][r] + bv;
        if (EPI == 1)
          v = 0.5f * v * (1.f + erff(v * 0.70710678118654752f));   // exact GELU
        Cb[(size_t)row * N + col] = (bf16_t)v;
      }
    }
  }
}

// ---------------- fused GEMM(BM=16, BN=256) + bias + residual + LayerNorm ----------------
// double-buffered; y = LN(resid + A@Bw^T + bias); grid = M/16 = 512 blocks (2/CU).
__global__ __launch_bounds__(256) void gemm_ln(
    const bf16_t* __restrict__ A, const bf16_t* __restrict__ Bw,
    const float* __restrict__ bias, const float* __restrict__ resid,
    const float* __restrict__ lnw, const float* __restrict__ lnb,
    float* __restrict__ xfout, bf16_t* __restrict__ xbout, int K) {
  __shared__ __align__(16) char smem[69632];
  bf16_t* As = (bf16_t*)smem;             // [2][16][64] = 4KB
  bf16_t* Bs = (bf16_t*)(smem + 4096);    // [2][256][64] = 64KB
  float*  E  = (float*)smem;              // epi: [16][258] f32 (aliases, after barrier)
  const int t = threadIdx.x;
  const int l = t & 63;
  const int w = t >> 6;
  const int bm = blockIdx.x * 16;

  f32x4 acc[4] = {};

  auto stage = [&](int buf, int k0) {
    if (w < 2) {   // A tile 16x64: waves 0,1 stage 8 rows each (1 issue)
      int row = w * 8 + (l >> 3), col = (l & 7) * 8;
      gload_lds16(A + (size_t)(bm + row) * K + (k0 + col), (void*)(As + buf * 1024 + w * 512));
    }
#pragma unroll
    for (int i = 0; i < 8; ++i) {   // B tile 256x64: 8 issues per wave
      int rr = (w * 8 + i) * 8 + (l >> 3), col = (l & 7) * 8;
      gload_lds16(Bw + (size_t)rr * K + (k0 + col), (void*)(Bs + buf * 16384 + (w * 8 + i) * 512));
    }
  };

  const int nt = K >> 6;
  stage(0, 0);
  for (int kt = 0; kt < nt; ++kt) {
    const int cur = kt & 1;
    if (kt + 1 < nt) {
      stage(cur ^ 1, (kt + 1) << 6);
      if (w < 2) asm volatile("s_waitcnt vmcnt(9)" ::: "memory");   // 1 A + 8 B in flight
      else       asm volatile("s_waitcnt vmcnt(8)" ::: "memory");   // 8 B in flight
    } else {
      asm volatile("s_waitcnt vmcnt(0)" ::: "memory");
    }
    __syncthreads();
#pragma unroll
    for (int kk = 0; kk < 2; ++kk) {
      bf16x8 af = *(const bf16x8*)(As + cur * 1024 + (l & 15) * 64 + kk * 32 + (l >> 4) * 8);
#pragma unroll
      for (int ni = 0; ni < 4; ++ni) {
        bf16x8 bfr = *(const bf16x8*)(Bs + cur * 16384 + (w * 64 + ni * 16 + (l & 15)) * 64 + kk * 32 + (l >> 4) * 8);
        acc[ni] = __builtin_amdgcn_mfma_f32_16x16x32_bf16(af, bfr, acc[ni], 0, 0, 0);
      }
    }
    __syncthreads();
  }

  // stash C+bias into LDS f32 [16][258]
  const int r0 = (l >> 4) * 4;
  const int cc = l & 15;
#pragma unroll
  for (int ni = 0; ni < 4; ++ni) {
    int col = w * 64 + ni * 16 + cc;
    float bv = bias[col];
#pragma unroll
    for (int r = 0; r < 4; ++r)
      E[(r0 + r) * 258 + col] = acc[ni][r] + bv;
  }
  __syncthreads();

  // LN: 16 threads per row, 16 cols per thread
  const int row = t >> 4;
  const int sub = t & 15;
  const float* ep = E + row * 258 + sub * 16;
  const float* rp = resid + (size_t)(bm + row) * 256 + sub * 16;
  float v[16];
  float s = 0.f;
#pragma unroll
  for (int j = 0; j < 4; ++j) {
    float4 a4 = ((const float4*)ep)[j];
    float4 b4 = ((const float4*)rp)[j];
    v[j * 4 + 0] = a4.x + b4.x; v[j * 4 + 1] = a4.y + b4.y;
    v[j * 4 + 2] = a4.z + b4.z; v[j * 4 + 3] = a4.w + b4.w;
    s += v[j * 4 + 0] + v[j * 4 + 1] + v[j * 4 + 2] + v[j * 4 + 3];
  }
#pragma unroll
  for (int o = 1; o < 16; o <<= 1) s += __shfl_xor(s, o);
  float mu = s * (1.f / 256.f);
  float e2 = 0.f;
#pragma unroll
  for (int j = 0; j < 16; ++j) { float d = v[j] - mu; e2 += d * d; }
#pragma unroll
  for (int o = 1; o < 16; o <<= 1) e2 += __shfl_xor(e2, o);
  float rs = rsqrtf(e2 * (1.f / 256.f) + 1e-5f);
  float* xo = xfout + (size_t)(bm + row) * 256 + sub * 16;
  bf16_t* xbo = xbout + (size_t)(bm + row) * 256 + sub * 16;
#pragma unroll
  for (int j = 0; j < 4; ++j) {
    float4 w4 = ((const float4*)(lnw + sub * 16))[j];
    float4 b4 = ((const float4*)(lnb + sub * 16))[j];
    float y0 = (v[j * 4 + 0] - mu) * rs * w4.x + b4.x;
    float y1 = (v[j * 4 + 1] - mu) * rs * w4.y + b4.y;
    float y2 = (v[j * 4 + 2] - mu) * rs * w4.z + b4.z;
    float y3 = (v[j * 4 + 3] - mu) * rs * w4.w + b4.w;
    float4 o4 = {y0, y1, y2, y3};
    ((float4*)xo)[j] = o4;
    bf16x4 ob;
    ob[0] = (bf16_t)y0; ob[1] = (bf16_t)y1; ob[2] = (bf16_t)y2; ob[3] = (bf16_t)y3;
    ((bf16x4*)xbo)[j] = ob;
  }
}

// ---------------- sparse attention: 4 rows/block, one wave per row, all-bf16 qkv ----------------
// qkvb layout: [8192][768] bf16 — q cols 0..255, k 256..511, v 512..767
__global__ __launch_bounds__(256) void k_attn2(
    const bf16_t* __restrict__ qkvb,
    const int* __restrict__ nbcol, const float* __restrict__ nbval,
    const int* __restrict__ nbcnt, bf16_t* __restrict__ aob) {
  const int w = threadIdx.x >> 6;
  const int l = threadIdx.x & 63;
  const int row = blockIdx.x * 4 + w;
  const int b = row >> 10;
  __shared__ float s_s[4][8][97];     // padded: conflict-free ph3
  __shared__ int   s_col[4][CAP];
  __shared__ float s_bias[4][CAP];
  __shared__ float s_den[4][8];
  const int deg = nbcnt[row];
  for (int j = l; j < deg; j += 64) {
    s_col[w][j] = nbcol[(size_t)row * CAP + j];
    s_bias[w][j] = nbval[(size_t)row * CAP + j];
  }
  const int h1 = l & 7;
  float q[32];
  {
    const bf16x8* qp = (const bf16x8*)(qkvb + (size_t)row * 768 + h1 * 32);
#pragma unroll
    for (int u = 0; u < 4; ++u) {
      bf16x8 t8 = qp[u];
#pragma unroll
      for (int j = 0; j < 8; ++j) q[u * 8 + j] = (float)t8[j];
    }
  }
  __syncthreads();

  const float scale = 0.17677669529663687f;   // 1/sqrt(32)
  const int nit = (deg + 7) >> 3;
  // phase 1: scores (8 nbrs x 8 heads per iter)
  float mx = -INFINITY;
  for (int it = 0; it < nit; ++it) {
    int idx = it * 8 + (l >> 3);
    float sc = -INFINITY;
    if (idx < deg) {
      int col = s_col[w][idx];
      const bf16x8* kr = (const bf16x8*)(qkvb + ((size_t)((b << 10) + col)) * 768 + 256 + h1 * 32);
      float d = 0.f;
#pragma unroll
      for (int u = 0; u < 4; ++u) {
        bf16x8 kv = kr[u];
#pragma unroll
        for (int j = 0; j < 8; ++j) d += (float)kv[j] * q[u * 8 + j];
      }
      sc = d * scale + s_bias[w][idx];
      s_s[w][h1][idx] = sc;
    }
    mx = fmaxf(mx, sc);
  }
#pragma unroll
  for (int o = 8; o < 64; o <<= 1) mx = fmaxf(mx, __shfl_xor(mx, o));
  __syncthreads();
  // phase 2: exp + denom
  float lsum = 0.f;
  for (int it = 0; it < nit; ++it) {
    int idx = it * 8 + (l >> 3);
    if (idx < deg) {
      float p = __expf(s_s[w][h1][idx] - mx);
      s_s[w][h1][idx] = p;
      lsum += p;
    }
  }
#pragma unroll
  for (int o = 8; o < 64; o <<= 1) lsum += __shfl_xor(lsum, o);
  if (l < 8) s_den[w][l] = lsum;
  __syncthreads();
  // phase 3: PV — all 64 lanes read one full V row per neighbor
  const int h3 = l >> 3;
  float a0 = 0.f, a1 = 0.f, a2 = 0.f, a3 = 0.f;
  const bf16_t* vbase = qkvb + ((size_t)(b << 10)) * 768 + 512 + l * 4;
#pragma unroll 4
  for (int idx = 0; idx < deg; ++idx) {
    float p = s_s[w][h3][idx];
    bf16x4 vv = *(const bf16x4*)(vbase + (size_t)s_col[w][idx] * 768);
    a0 += p * (float)vv[0]; a1 += p * (float)vv[1];
    a2 += p * (float)vv[2]; a3 += p * (float)vv[3];
  }
  float rden = 1.f / s_den[w][h3];
  bf16x4 o;
  o[0] = (bf16_t)(a0 * rden); o[1] = (bf16_t)(a1 * rden);
  o[2] = (bf16_t)(a2 * rden); o[3] = (bf16_t)(a3 * rden);
  *(bf16x4*)(aob + (size_t)row * 256 + l * 4) = o;
}

// ---------------- final LayerNorm (no residual), wave per row ----------------
__global__ __launch_bounds__(256) void k_ln(
    const float* __restrict__ xin,
    const float* __restrict__ w, const float* __restrict__ b,
    float* __restrict__ xout) {
  int r = blockIdx.x * 4 + (threadIdx.x >> 6);
  int l = threadIdx.x & 63;
  float4 v = ((const float4*)(xin + (size_t)r * 256))[l];
  float s = v.x + v.y + v.z + v.w;
#pragma unroll
  for (int o = 32; o; o >>= 1) s += __shfl_xor(s, o);
  float mu = s * (1.f / 256.f);
  float dx = v.x - mu, dy = v.y - mu, dz = v.z - mu, dw = v.w - mu;
  float e = dx * dx + dy * dy + dz * dz + dw * dw;
#pragma unroll
  for (int o = 32; o; o >>= 1) e += __shfl_xor(e, o);
  float rs = rsqrtf(e * (1.f / 256.f) + 1e-5f);
  float4 wv = ((const float4*)w)[l];
  float4 bv = ((const float4*)b)[l];
  float4 o4 = {dx * rs * wv.x + bv.x, dy * rs * wv.y + bv.y,
               dz * rs * wv.z + bv.z, dw * rs * wv.w + bv.w};
  ((float4*)(xout + (size_t)r * 256))[l] = o4;
}

extern "C" void kernel_launch(void* const* d_in, const int* in_sizes, int n_in,
                              void* d_out, int out_size, void* d_ws, size_t ws_size,
                              hipStream_t stream) {
  const float* H    = (const float*)d_in[0];
  const int*   ei   = (const int*)d_in[1];
  const float* m    = (const float*)d_in[2];
  const float* Wqkv = (const float*)d_in[3];
  const float* bqkv = (const float*)d_in[4];
  const float* Wo   = (const float*)d_in[5];
  const float* bo   = (const float*)d_in[6];
  const float* ln1w = (const float*)d_in[7];
  const float* ln1b = (const float*)d_in[8];
  const float* W1   = (const float*)d_in[9];
  const float* b1   = (const float*)d_in[10];
  const float* W2   = (const float*)d_in[11];
  const float* b2   = (const float*)d_in[12];
  const float* ln2w = (const float*)d_in[13];
  const float* ln2b = (const float*)d_in[14];
  const float* lnfw = (const float*)d_in[15];
  const float* lnfb = (const float*)d_in[16];

  char* ws = (char*)d_ws;
  size_t off = 0;
  auto alloc = [&](size_t bytes) {
    void* p = ws + off;
    off += (bytes + 255) & ~(size_t)255;
    return p;
  };

  int*    cnt   = (int*)alloc((size_t)BATCH * NTOK * 4);
  int*    ent   = (int*)alloc((size_t)BATCH * NTOK * CAP * 4);
  int*    nbcol = (int*)alloc((size_t)BATCH * NTOK * CAP * 4);
  float*  nbval = (float*)alloc((size_t)BATCH * NTOK * CAP * 4);
  int*    nbcnt = (int*)alloc((size_t)BATCH * NTOK * 4);
  bf16_t* qkvb  = (bf16_t*)alloc((size_t)8192 * 768 * 2);
  bf16_t* wqkvb = (bf16_t*)alloc((size_t)2 * 768 * 256 * 2);
  bf16_t* wob   = (bf16_t*)alloc((size_t)2 * 256 * 256 * 2);
  bf16_t* w1b   = (bf16_t*)alloc((size_t)2 * 1024 * 256 * 2);
  bf16_t* w2b   = (bf16_t*)alloc((size_t)2 * 256 * 1024 * 2);
  bf16_t* xb    = (bf16_t*)alloc((size_t)8192 * 256 * 2);
  bf16_t* aob   = (bf16_t*)alloc((size_t)8192 * 256 * 2);
  bf16_t* ffb   = (bf16_t*)alloc((size_t)8192 * 1024 * 2);
  float*  xfA   = (float*)alloc((size_t)8192 * 256 * 4);
  float*  xfB   = (float*)alloc((size_t)8192 * 256 * 4);

  k_pre<<<3584, 256, 0, stream>>>((int4*)cnt, H, Wqkv, Wo, W1, W2,
                                  xb, wqkvb, wob, w1b, w2b);
  k_scatter2<<<(BATCH * NEDGE + 255) / 256, 256, 0, stream>>>(ei, cnt, ent);
  k_build2<<<BATCH * NTOK / 4, 256, 0, stream>>>(cnt, ent, m, nbcol, nbval, nbcnt);

  const float* r1[2] = {H, xfB};    // residual input to ln1 per layer
  for (int lyr = 0; lyr < 2; ++lyr) {
    gemm_bt<3><<<dim3(768 / 128, 8192 / 128), 256, 0, stream>>>(
        xb, wqkvb + (size_t)lyr * 768 * 256, bqkv + lyr * 768, qkvb, 8192, 768, 256);
    k_attn2<<<BATCH * NTOK / 4, 256, 0, stream>>>(qkvb, nbcol, nbval, nbcnt, aob);
    gemm_ln<<<512, 256, 0, stream>>>(
        aob, wob + (size_t)lyr * 256 * 256, bo + lyr * 256, r1[lyr],
        ln1w + lyr * 256, ln1b + lyr * 256, xfA, xb, 256);
    gemm_bt<1><<<dim3(1024 / 128, 8192 / 128), 256, 0, stream>>>(
        xb, w1b + (size_t)lyr * 1024 * 256, b1 + lyr * 1024, ffb, 8192, 1024, 256);
    gemm_ln<<<512, 256, 0, stream>>>(
        ffb, w2b + (size_t)lyr * 256 * 1024, b2 + lyr * 256, xfA,
        ln2w + lyr * 256, ln2b + lyr * 256, xfB, xb, 1024);
  }
  k_ln<<<8192 / 4, 256, 0, stream>>>(xfB, lnfw, lnfb, (float*)d_out);
}

// Round 8
// 210.427 us; speedup vs baseline: 1.1127x; 1.0949x over previous
//
#include <hip/hip_runtime.h>
#include <hip/hip_bf16.h>
#include <math.h>

typedef __bf16 bf16_t;
typedef __attribute__((ext_vector_type(8))) __bf16 bf16x8;
typedef __attribute__((ext_vector_type(4))) __bf16 bf16x4;
typedef __attribute__((ext_vector_type(4))) float f32x4;

#define BATCH 8
#define NTOK 1024
#define NEDGE 16384
#define CAP 96   // max entries per row (deg ~ Poisson(32); P(deg>96) < 1e-20)

// ---------------- async global->LDS (16B per lane, wave-uniform LDS base) ----------------
__device__ __forceinline__ void gload_lds16(const void* g, void* l) {
  __builtin_amdgcn_global_load_lds(
      (const __attribute__((address_space(1))) unsigned int*)(uintptr_t)g,
      (__attribute__((address_space(3))) unsigned int*)(unsigned int)(uintptr_t)l,
      16, 0, 0);
}

// ---------------- fused: f32->bf16 cvt for H + weights; blocks <8 also zero cnt ----------------
__global__ void k_pre(int4* __restrict__ cnt,
                      const float* __restrict__ H, const float* __restrict__ Wqkv,
                      const float* __restrict__ Wo, const float* __restrict__ W1,
                      const float* __restrict__ W2, bf16_t* __restrict__ xb,
                      bf16_t* __restrict__ wqkvb, bf16_t* __restrict__ wob,
                      bf16_t* __restrict__ w1b, bf16_t* __restrict__ w2b) {
  int i = blockIdx.x * 256 + threadIdx.x;   // float4-quad index
  if (blockIdx.x < 8) {
    int4 z = {0, 0, 0, 0};
    cnt[i] = z;                             // 8 blocks x 256 x int4 = 8192 ints
  }
  const float* s; bf16_t* d; int off;
  if (i < 524288)      { s = H;    d = xb;    off = i; }
  else if (i < 622592) { s = Wqkv; d = wqkvb; off = i - 524288; }
  else if (i < 655360) { s = Wo;   d = wob;   off = i - 622592; }
  else if (i < 786432) { s = W1;   d = w1b;   off = i - 655360; }
  else if (i < 917504) { s = W2;   d = w2b;   off = i - 786432; }
  else return;
  float4 v = ((const float4*)s)[off];
  bf16x4 o;
  o[0] = (bf16_t)v.x; o[1] = (bf16_t)v.y; o[2] = (bf16_t)v.z; o[3] = (bf16_t)v.w;
  ((bf16x4*)d)[off] = o;
}

// ---------------- edge scatter: packed (prio<<10|col) appended to per-row lists ----------------
__global__ void k_scatter2(const int* __restrict__ ei, int* __restrict__ cnt,
                           int* __restrict__ ent) {
  int idx = blockIdx.x * 256 + threadIdx.x;
  if (idx >= BATCH * NEDGE) return;
  int b = idx >> 14;
  int e = idx & (NEDGE - 1);
  const int* eb = ei + (size_t)b * 2 * NEDGE;
  int r = eb[e], c = eb[NEDGE + e];
  int rowr = (b << 10) + r, rowc = (b << 10) + c;
  int q = atomicAdd(cnt + rowr, 1);
  if (q < CAP) ent[rowr * CAP + q] = ((e + 1) << 10) | c;
  q = atomicAdd(cnt + rowc, 1);
  if (q < CAP) ent[rowc * CAP + q] = ((NEDGE + e + 1) << 10) | r;
}

// ---------------- CSR build v2: dedup per row in LDS, canonical ascending-col order ----------------
__global__ __launch_bounds__(256) void k_build2(
    const int* __restrict__ cnt, const int* __restrict__ ent,
    const float* __restrict__ mptr,
    int* __restrict__ nbcol, float* __restrict__ nbval, int* __restrict__ nbcnt) {
  const int w = threadIdx.x >> 6;
  const int l = threadIdx.x & 63;
  const int row = blockIdx.x * 4 + w;   // b*1024 + i
  const int i = row & 1023;
  const int b = row >> 10;
  __shared__ int sE[4][CAP];
  __shared__ int sW[4][CAP];
  const int n = min(cnt[row], CAP);
  for (int j = l; j < n; j += 64) sE[w][j] = ent[(size_t)row * CAP + j];
  __syncthreads();

  bool dcov_l = false;
  bool win[2] = {false, false};
  int myc[2], myp[2];
#pragma unroll
  for (int s = 0; s < 2; ++s) {
    int k = s * 64 + l;
    if (k < n) {
      int pk = sE[w][k], ck = pk & 1023;
      myc[s] = ck; myp[s] = pk;
      bool wn = true;
      for (int j = 0; j < n; ++j) {
        int pj = sE[w][j];
        if ((pj & 1023) == ck && pj > pk) wn = false;
      }
      win[s] = wn;
      sW[w][k] = wn ? 1 : 0;
      if (ck == i) dcov_l = true;
    }
  }
  const bool dcov = __any(dcov_l);
  unsigned long long m0 = __ballot(win[0]);
  unsigned long long m1 = __ballot(win[1]);
  if (l == 0) nbcnt[row] = __popcll(m0) + __popcll(m1) + (dcov ? 0 : 1);

#pragma unroll
  for (int s = 0; s < 2; ++s) {
    int k = s * 64 + l;
    if (k < n && win[s]) {
      int pos = 0;
      for (int j = 0; j < n; ++j)
        if (sW[w][j] && (sE[w][j] & 1023) < myc[s]) ++pos;
      if (!dcov && i < myc[s]) ++pos;
      int e = ((myp[s] >> 10) - 1) & (NEDGE - 1);
      float v = logf(mptr[(size_t)b * NEDGE + e] + 1e-9f);
      if (pos < CAP) {
        nbcol[(size_t)row * CAP + pos] = myc[s];
        nbval[(size_t)row * CAP + pos] = v;
      }
    }
  }
  if (!dcov && l == 0) {   // virtual diagonal (value 0)
    int pos = 0;
    for (int j = 0; j < n; ++j)
      if (sW[w][j] && (sE[w][j] & 1023) < i) ++pos;
    nbcol[(size_t)row * CAP + pos] = i;
    nbval[(size_t)row * CAP + pos] = 0.f;
  }
}

// ---------------- GEMM 128x128, double-buffered LDS + counted vmcnt ----------------
// EPI 1: gelu -> bf16 out. EPI 3: plain bf16 out.
template <int EPI>
__global__ __launch_bounds__(256) void gemm_bt(
    const bf16_t* __restrict__ A, const bf16_t* __restrict__ Bw,
    const float* __restrict__ bias, bf16_t* __restrict__ Cb,
    int M, int N, int K) {
  __shared__ bf16_t As[2][128 * 64];
  __shared__ bf16_t Bs[2][128 * 64];
  const int t = threadIdx.x;
  const int l = t & 63;
  const int w = t >> 6;
  const int wr = w >> 1, wc = w & 1;
  const int bm = blockIdx.y * 128, bn = blockIdx.x * 128;

  f32x4 acc[4][4] = {};

  auto stage = [&](int buf, int k0) {
#pragma unroll
    for (int i = 0; i < 4; ++i) {
      int idx = i * 2048 + t * 8;
      int row = idx >> 6;
      int col = idx & 63;
      gload_lds16(A + (size_t)(bm + row) * K + (k0 + col), (void*)(&As[buf][0] + i * 2048 + w * 512));
      gload_lds16(Bw + (size_t)(bn + row) * K + (k0 + col), (void*)(&Bs[buf][0] + i * 2048 + w * 512));
    }
  };

  const int nt = K >> 6;
  stage(0, 0);
  for (int kt = 0; kt < nt; ++kt) {
    const int cur = kt & 1;
    if (kt + 1 < nt) {
      stage(cur ^ 1, (kt + 1) << 6);
      asm volatile("s_waitcnt vmcnt(8)" ::: "memory");
    } else {
      asm volatile("s_waitcnt vmcnt(0)" ::: "memory");
    }
    __syncthreads();
#pragma unroll
    for (int kk = 0; kk < 2; ++kk) {
      bf16x8 af[4], bfr[4];
#pragma unroll
      for (int mi = 0; mi < 4; ++mi)
        af[mi] = *(const bf16x8*)(&As[cur][0] + (wr * 64 + mi * 16 + (l & 15)) * 64 + kk * 32 + (l >> 4) * 8);
#pragma unroll
      for (int ni = 0; ni < 4; ++ni)
        bfr[ni] = *(const bf16x8*)(&Bs[cur][0] + (wc * 64 + ni * 16 + (l & 15)) * 64 + kk * 32 + (l >> 4) * 8);
#pragma unroll
      for (int mi = 0; mi < 4; ++mi)
#pragma unroll
        for (int ni = 0; ni < 4; ++ni)
          acc[mi][ni] = __builtin_amdgcn_mfma_f32_16x16x32_bf16(af[mi], bfr[ni], acc[mi][ni], 0, 0, 0);
    }
    __syncthreads();
  }

  const int r0 = (l >> 4) * 4;   // C/D: row=(lane>>4)*4+reg, col=lane&15
  const int cc = l & 15;
#pragma unroll
  for (int mi = 0; mi < 4; ++mi) {
#pragma unroll
    for (int ni = 0; ni < 4; ++ni) {
      int col = bn + wc * 64 + ni * 16 + cc;
      float bv = bias[col];
#pragma unroll
      for (int r = 0; r < 4; ++r) {
        int row = bm + wr * 64 + mi * 16 + r0 + r;
        float v = acc[mi][ni][r] + bv;
        if (EPI == 1)
          v = 0.5f * v * (1.f + erff(v * 0.70710678118654752f));   // exact GELU
        Cb[(size_t)row * N + col] = (bf16_t)v;
      }
    }
  }
}

// ---------------- fused GEMM(BM=16, BN=256) + bias + bf16-residual + LayerNorm ----------------
// FIN=0: y=LN(resid+A@Bw^T+bias) -> bf16 xbout. FIN=1: additionally lnf(y) -> f32 outf (d_out).
template <int FIN>
__global__ __launch_bounds__(256) void gemm_ln(
    const bf16_t* __restrict__ A, const bf16_t* __restrict__ Bw,
    const float* __restrict__ bias, const bf16_t* __restrict__ residb,
    const float* __restrict__ lnw, const float* __restrict__ lnb,
    const float* __restrict__ lnfw, const float* __restrict__ lnfb,
    bf16_t* __restrict__ xbout, float* __restrict__ outf, int K) {
  __shared__ __align__(16) char smem[69632];
  bf16_t* As = (bf16_t*)smem;             // [2][16][64] = 4KB
  bf16_t* Bs = (bf16_t*)(smem + 4096);    // [2][256][64] = 64KB
  float*  E  = (float*)smem;              // epi: [16][258] f32 (aliases, after barrier)
  const int t = threadIdx.x;
  const int l = t & 63;
  const int w = t >> 6;
  const int bm = blockIdx.x * 16;

  f32x4 acc[4] = {};

  auto stage = [&](int buf, int k0) {
    if (w < 2) {   // A tile 16x64: waves 0,1 stage 8 rows each (1 issue)
      int row = w * 8 + (l >> 3), col = (l & 7) * 8;
      gload_lds16(A + (size_t)(bm + row) * K + (k0 + col), (void*)(As + buf * 1024 + w * 512));
    }
#pragma unroll
    for (int i = 0; i < 8; ++i) {   // B tile 256x64: 8 issues per wave
      int rr = (w * 8 + i) * 8 + (l >> 3), col = (l & 7) * 8;
      gload_lds16(Bw + (size_t)rr * K + (k0 + col), (void*)(Bs + buf * 16384 + (w * 8 + i) * 512));
    }
  };

  const int nt = K >> 6;
  stage(0, 0);
  for (int kt = 0; kt < nt; ++kt) {
    const int cur = kt & 1;
    if (kt + 1 < nt) {
      stage(cur ^ 1, (kt + 1) << 6);
      if (w < 2) asm volatile("s_waitcnt vmcnt(9)" ::: "memory");
      else       asm volatile("s_waitcnt vmcnt(8)" ::: "memory");
    } else {
      asm volatile("s_waitcnt vmcnt(0)" ::: "memory");
    }
    __syncthreads();
#pragma unroll
    for (int kk = 0; kk < 2; ++kk) {
      bf16x8 af = *(const bf16x8*)(As + cur * 1024 + (l & 15) * 64 + kk * 32 + (l >> 4) * 8);
#pragma unroll
      for (int ni = 0; ni < 4; ++ni) {
        bf16x8 bfr = *(const bf16x8*)(Bs + cur * 16384 + (w * 64 + ni * 16 + (l & 15)) * 64 + kk * 32 + (l >> 4) * 8);
        acc[ni] = __builtin_amdgcn_mfma_f32_16x16x32_bf16(af, bfr, acc[ni], 0, 0, 0);
      }
    }
    __syncthreads();
  }

  // stash C+bias into LDS f32 [16][258]
  const int r0 = (l >> 4) * 4;
  const int cc = l & 15;
#pragma unroll
  for (int ni = 0; ni < 4; ++ni) {
    int col = w * 64 + ni * 16 + cc;
    float bv = bias[col];
#pragma unroll
    for (int r = 0; r < 4; ++r)
      E[(r0 + r) * 258 + col] = acc[ni][r] + bv;
  }
  __syncthreads();

  // LN: 16 threads per row, 16 cols per thread; residual from bf16
  const int row = t >> 4;
  const int sub = t & 15;
  const float* ep = E + row * 258 + sub * 16;
  const bf16_t* rp = residb + (size_t)(bm + row) * 256 + sub * 16;
  float v[16];
  float s = 0.f;
#pragma unroll
  for (int j = 0; j < 4; ++j) {
    float4 a4 = ((const float4*)ep)[j];
    bf16x4 r4 = ((const bf16x4*)rp)[j];
    v[j * 4 + 0] = a4.x + (float)r4[0]; v[j * 4 + 1] = a4.y + (float)r4[1];
    v[j * 4 + 2] = a4.z + (float)r4[2]; v[j * 4 + 3] = a4.w + (float)r4[3];
    s += v[j * 4 + 0] + v[j * 4 + 1] + v[j * 4 + 2] + v[j * 4 + 3];
  }
#pragma unroll
  for (int o = 1; o < 16; o <<= 1) s += __shfl_xor(s, o);
  float mu = s * (1.f / 256.f);
  float e2 = 0.f;
#pragma unroll
  for (int j = 0; j < 16; ++j) { float d = v[j] - mu; e2 += d * d; }
#pragma unroll
  for (int o = 1; o < 16; o <<= 1) e2 += __shfl_xor(e2, o);
  float rs = rsqrtf(e2 * (1.f / 256.f) + 1e-5f);
  float y[16];
#pragma unroll
  for (int j = 0; j < 4; ++j) {
    float4 w4 = ((const float4*)(lnw + sub * 16))[j];
    float4 b4 = ((const float4*)(lnb + sub * 16))[j];
    y[j * 4 + 0] = (v[j * 4 + 0] - mu) * rs * w4.x + b4.x;
    y[j * 4 + 1] = (v[j * 4 + 1] - mu) * rs * w4.y + b4.y;
    y[j * 4 + 2] = (v[j * 4 + 2] - mu) * rs * w4.z + b4.z;
    y[j * 4 + 3] = (v[j * 4 + 3] - mu) * rs * w4.w + b4.w;
  }
  if (FIN == 0) {
    bf16_t* xbo = xbout + (size_t)(bm + row) * 256 + sub * 16;
#pragma unroll
    for (int j = 0; j < 4; ++j) {
      bf16x4 ob;
      ob[0] = (bf16_t)y[j * 4 + 0]; ob[1] = (bf16_t)y[j * 4 + 1];
      ob[2] = (bf16_t)y[j * 4 + 2]; ob[3] = (bf16_t)y[j * 4 + 3];
      ((bf16x4*)xbo)[j] = ob;
    }
  } else {
    // fused final LayerNorm on y
    float s2 = 0.f;
#pragma unroll
    for (int j = 0; j < 16; ++j) s2 += y[j];
#pragma unroll
    for (int o = 1; o < 16; o <<= 1) s2 += __shfl_xor(s2, o);
    float mu2 = s2 * (1.f / 256.f);
    float q2 = 0.f;
#pragma unroll
    for (int j = 0; j < 16; ++j) { float d = y[j] - mu2; q2 += d * d; }
#pragma unroll
    for (int o = 1; o < 16; o <<= 1) q2 += __shfl_xor(q2, o);
    float rs2 = rsqrtf(q2 * (1.f / 256.f) + 1e-5f);
    float* xo = outf + (size_t)(bm + row) * 256 + sub * 16;
#pragma unroll
    for (int j = 0; j < 4; ++j) {
      float4 w4 = ((const float4*)(lnfw + sub * 16))[j];
      float4 b4 = ((const float4*)(lnfb + sub * 16))[j];
      float4 o4 = {(y[j * 4 + 0] - mu2) * rs2 * w4.x + b4.x,
                   (y[j * 4 + 1] - mu2) * rs2 * w4.y + b4.y,
                   (y[j * 4 + 2] - mu2) * rs2 * w4.z + b4.z,
                   (y[j * 4 + 3] - mu2) * rs2 * w4.w + b4.w};
      ((float4*)xo)[j] = o4;
    }
  }
}

// ---------------- sparse attention: XCD-swizzled (batch = bid&7), 4 rows/block ----------------
// qkvb layout: [8192][768] bf16 — q cols 0..255, k 256..511, v 512..767
__global__ __launch_bounds__(256) void k_attn2(
    const bf16_t* __restrict__ qkvb,
    const int* __restrict__ nbcol, const float* __restrict__ nbval,
    const int* __restrict__ nbcnt, bf16_t* __restrict__ aob) {
  const int w = threadIdx.x >> 6;
  const int l = threadIdx.x & 63;
  // swizzle: each XCD (bid%8) works one batch -> K/V stays L2-resident per XCD
  const int b = blockIdx.x & 7;
  const int row = (b << 10) + (blockIdx.x >> 3) * 4 + w;
  __shared__ float s_s[4][8][97];     // padded: conflict-free ph3
  __shared__ int   s_col[4][CAP];
  __shared__ float s_bias[4][CAP];
  __shared__ float s_den[4][8];
  const int deg = nbcnt[row];
  for (int j = l; j < deg; j += 64) {
    s_col[w][j] = nbcol[(size_t)row * CAP + j];
    s_bias[w][j] = nbval[(size_t)row * CAP + j];
  }
  const int h1 = l & 7;
  float q[32];
  {
    const bf16x8* qp = (const bf16x8*)(qkvb + (size_t)row * 768 + h1 * 32);
#pragma unroll
    for (int u = 0; u < 4; ++u) {
      bf16x8 t8 = qp[u];
#pragma unroll
      for (int j = 0; j < 8; ++j) q[u * 8 + j] = (float)t8[j];
    }
  }
  __syncthreads();

  const float scale = 0.17677669529663687f;   // 1/sqrt(32)
  const int nit = (deg + 7) >> 3;
  float mx = -INFINITY;
  for (int it = 0; it < nit; ++it) {
    int idx = it * 8 + (l >> 3);
    float sc = -INFINITY;
    if (idx < deg) {
      int col = s_col[w][idx];
      const bf16x8* kr = (const bf16x8*)(qkvb + ((size_t)((b << 10) + col)) * 768 + 256 + h1 * 32);
      float d = 0.f;
#pragma unroll
      for (int u = 0; u < 4; ++u) {
        bf16x8 kv = kr[u];
#pragma unroll
        for (int j = 0; j < 8; ++j) d += (float)kv[j] * q[u * 8 + j];
      }
      sc = d * scale + s_bias[w][idx];
      s_s[w][h1][idx] = sc;
    }
    mx = fmaxf(mx, sc);
  }
#pragma unroll
  for (int o = 8; o < 64; o <<= 1) mx = fmaxf(mx, __shfl_xor(mx, o));
  __syncthreads();
  float lsum = 0.f;
  for (int it = 0; it < nit; ++it) {
    int idx = it * 8 + (l >> 3);
    if (idx < deg) {
      float p = __expf(s_s[w][h1][idx] - mx);
      s_s[w][h1][idx] = p;
      lsum += p;
    }
  }
#pragma unroll
  for (int o = 8; o < 64; o <<= 1) lsum += __shfl_xor(lsum, o);
  if (l < 8) s_den[w][l] = lsum;
  __syncthreads();
  const int h3 = l >> 3;
  float a0 = 0.f, a1 = 0.f, a2 = 0.f, a3 = 0.f;
  const bf16_t* vbase = qkvb + ((size_t)(b << 10)) * 768 + 512 + l * 4;
#pragma unroll 4
  for (int idx = 0; idx < deg; ++idx) {
    float p = s_s[w][h3][idx];
    bf16x4 vv = *(const bf16x4*)(vbase + (size_t)s_col[w][idx] * 768);
    a0 += p * (float)vv[0]; a1 += p * (float)vv[1];
    a2 += p * (float)vv[2]; a3 += p * (float)vv[3];
  }
  float rden = 1.f / s_den[w][h3];
  bf16x4 o;
  o[0] = (bf16_t)(a0 * rden); o[1] = (bf16_t)(a1 * rden);
  o[2] = (bf16_t)(a2 * rden); o[3] = (bf16_t)(a3 * rden);
  *(bf16x4*)(aob + (size_t)row * 256 + l * 4) = o;
}

extern "C" void kernel_launch(void* const* d_in, const int* in_sizes, int n_in,
                              void* d_out, int out_size, void* d_ws, size_t ws_size,
                              hipStream_t stream) {
  const float* H    = (const float*)d_in[0];
  const int*   ei   = (const int*)d_in[1];
  const float* m    = (const float*)d_in[2];
  const float* Wqkv = (const float*)d_in[3];
  const float* bqkv = (const float*)d_in[4];
  const float* Wo   = (const float*)d_in[5];
  const float* bo   = (const float*)d_in[6];
  const float* ln1w = (const float*)d_in[7];
  const float* ln1b = (const float*)d_in[8];
  const float* W1   = (const float*)d_in[9];
  const float* b1   = (const float*)d_in[10];
  const float* W2   = (const float*)d_in[11];
  const float* b2   = (const float*)d_in[12];
  const float* ln2w = (const float*)d_in[13];
  const float* ln2b = (const float*)d_in[14];
  const float* lnfw = (const float*)d_in[15];
  const float* lnfb = (const float*)d_in[16];

  char* ws = (char*)d_ws;
  size_t off = 0;
  auto alloc = [&](size_t bytes) {
    void* p = ws + off;
    off += (bytes + 255) & ~(size_t)255;
    return p;
  };

  int*    cnt   = (int*)alloc((size_t)BATCH * NTOK * 4);
  int*    ent   = (int*)alloc((size_t)BATCH * NTOK * CAP * 4);
  int*    nbcol = (int*)alloc((size_t)BATCH * NTOK * CAP * 4);
  float*  nbval = (float*)alloc((size_t)BATCH * NTOK * CAP * 4);
  int*    nbcnt = (int*)alloc((size_t)BATCH * NTOK * 4);
  bf16_t* qkvb  = (bf16_t*)alloc((size_t)8192 * 768 * 2);
  bf16_t* wqkvb = (bf16_t*)alloc((size_t)2 * 768 * 256 * 2);
  bf16_t* wob   = (bf16_t*)alloc((size_t)2 * 256 * 256 * 2);
  bf16_t* w1b   = (bf16_t*)alloc((size_t)2 * 1024 * 256 * 2);
  bf16_t* w2b   = (bf16_t*)alloc((size_t)2 * 256 * 1024 * 2);
  bf16_t* xb    = (bf16_t*)alloc((size_t)8192 * 256 * 2);   // layer input x (bf16)
  bf16_t* x1b   = (bf16_t*)alloc((size_t)8192 * 256 * 2);   // after ln1
  bf16_t* aob   = (bf16_t*)alloc((size_t)8192 * 256 * 2);
  bf16_t* ffb   = (bf16_t*)alloc((size_t)8192 * 1024 * 2);

  k_pre<<<3584, 256, 0, stream>>>((int4*)cnt, H, Wqkv, Wo, W1, W2,
                                  xb, wqkvb, wob, w1b, w2b);
  k_scatter2<<<(BATCH * NEDGE + 255) / 256, 256, 0, stream>>>(ei, cnt, ent);
  k_build2<<<BATCH * NTOK / 4, 256, 0, stream>>>(cnt, ent, m, nbcol, nbval, nbcnt);

  for (int lyr = 0; lyr < 2; ++lyr) {
    gemm_bt<3><<<dim3(768 / 128, 8192 / 128), 256, 0, stream>>>(
        xb, wqkvb + (size_t)lyr * 768 * 256, bqkv + lyr * 768, qkvb, 8192, 768, 256);
    k_attn2<<<BATCH * NTOK / 4, 256, 0, stream>>>(qkvb, nbcol, nbval, nbcnt, aob);
    gemm_ln<0><<<512, 256, 0, stream>>>(
        aob, wob + (size_t)lyr * 256 * 256, bo + lyr * 256, xb,
        ln1w + lyr * 256, ln1b + lyr * 256, nullptr, nullptr, x1b, nullptr, 256);
    gemm_bt<1><<<dim3(1024 / 128, 8192 / 128), 256, 0, stream>>>(
        x1b, w1b + (size_t)lyr * 1024 * 256, b1 + lyr * 1024, ffb, 8192, 1024, 256);
    if (lyr == 0) {
      gemm_ln<0><<<512, 256, 0, stream>>>(
          ffb, w2b + (size_t)lyr * 256 * 1024, b2 + lyr * 256, x1b,
          ln2w + lyr * 256, ln2b + lyr * 256, nullptr, nullptr, xb, nullptr, 1024);
    } else {
      gemm_ln<1><<<512, 256, 0, stream>>>(
          ffb, w2b + (size_t)lyr * 256 * 1024, b2 + lyr * 256, x1b,
          ln2w + lyr * 256, ln2b + lyr * 256, lnfw, lnfb, nullptr, (float*)d_out, 1024);
    }
  }
}

// Round 9
// 197.991 us; speedup vs baseline: 1.1826x; 1.0628x over previous
//
#include <hip/hip_runtime.h>
#include <hip/hip_bf16.h>
#include <math.h>

typedef __bf16 bf16_t;
typedef __attribute__((ext_vector_type(8))) __bf16 bf16x8;
typedef __attribute__((ext_vector_type(4))) __bf16 bf16x4;
typedef __attribute__((ext_vector_type(4))) float f32x4;

#define BATCH 8
#define NTOK 1024
#define NEDGE 16384
#define CAP 96   // max entries per row (deg ~ Poisson(32); P(deg>96) < 1e-20)

// ---------------- async global->LDS (16B per lane, wave-uniform LDS base) ----------------
__device__ __forceinline__ void gload_lds16(const void* g, void* l) {
  __builtin_amdgcn_global_load_lds(
      (const __attribute__((address_space(1))) unsigned int*)(uintptr_t)g,
      (__attribute__((address_space(3))) unsigned int*)(unsigned int)(uintptr_t)l,
      16, 0, 0);
}

// ---------------- fused: f32->bf16 cvt for H + weights; blocks <8 also zero cnt ----------------
__global__ void k_pre(int4* __restrict__ cnt,
                      const float* __restrict__ H, const float* __restrict__ Wqkv,
                      const float* __restrict__ Wo, const float* __restrict__ W1,
                      const float* __restrict__ W2, bf16_t* __restrict__ xb,
                      bf16_t* __restrict__ wqkvb, bf16_t* __restrict__ wob,
                      bf16_t* __restrict__ w1b, bf16_t* __restrict__ w2b) {
  int i = blockIdx.x * 256 + threadIdx.x;   // float4-quad index
  if (blockIdx.x < 8) {
    int4 z = {0, 0, 0, 0};
    cnt[i] = z;                             // 8 blocks x 256 x int4 = 8192 ints
  }
  const float* s; bf16_t* d; int off;
  if (i < 524288)      { s = H;    d = xb;    off = i; }
  else if (i < 622592) { s = Wqkv; d = wqkvb; off = i - 524288; }
  else if (i < 655360) { s = Wo;   d = wob;   off = i - 622592; }
  else if (i < 786432) { s = W1;   d = w1b;   off = i - 655360; }
  else if (i < 917504) { s = W2;   d = w2b;   off = i - 786432; }
  else return;
  float4 v = ((const float4*)s)[off];
  bf16x4 o;
  o[0] = (bf16_t)v.x; o[1] = (bf16_t)v.y; o[2] = (bf16_t)v.z; o[3] = (bf16_t)v.w;
  ((bf16x4*)d)[off] = o;
}

// ---------------- edge scatter: packed (prio<<10|col) appended to per-row lists ----------------
__global__ void k_scatter2(const int* __restrict__ ei, int* __restrict__ cnt,
                           int* __restrict__ ent) {
  int idx = blockIdx.x * 256 + threadIdx.x;
  if (idx >= BATCH * NEDGE) return;
  int b = idx >> 14;
  int e = idx & (NEDGE - 1);
  const int* eb = ei + (size_t)b * 2 * NEDGE;
  int r = eb[e], c = eb[NEDGE + e];
  int rowr = (b << 10) + r, rowc = (b << 10) + c;
  int q = atomicAdd(cnt + rowr, 1);
  if (q < CAP) ent[rowr * CAP + q] = ((e + 1) << 10) | c;
  q = atomicAdd(cnt + rowc, 1);
  if (q < CAP) ent[rowc * CAP + q] = ((NEDGE + e + 1) << 10) | r;
}

// ---------------- CSR build v2: dedup per row in LDS, canonical ascending-col order ----------------
__global__ __launch_bounds__(256) void k_build2(
    const int* __restrict__ cnt, const int* __restrict__ ent,
    const float* __restrict__ mptr,
    int* __restrict__ nbcol, float* __restrict__ nbval, int* __restrict__ nbcnt) {
  const int w = threadIdx.x >> 6;
  const int l = threadIdx.x & 63;
  const int row = blockIdx.x * 4 + w;   // b*1024 + i
  const int i = row & 1023;
  const int b = row >> 10;
  __shared__ int sE[4][CAP];
  __shared__ int sW[4][CAP];
  const int n = min(cnt[row], CAP);
  for (int j = l; j < n; j += 64) sE[w][j] = ent[(size_t)row * CAP + j];
  __syncthreads();

  bool dcov_l = false;
  bool win[2] = {false, false};
  int myc[2], myp[2];
#pragma unroll
  for (int s = 0; s < 2; ++s) {
    int k = s * 64 + l;
    if (k < n) {
      int pk = sE[w][k], ck = pk & 1023;
      myc[s] = ck; myp[s] = pk;
      bool wn = true;
      for (int j = 0; j < n; ++j) {
        int pj = sE[w][j];
        if ((pj & 1023) == ck && pj > pk) wn = false;
      }
      win[s] = wn;
      sW[w][k] = wn ? 1 : 0;
      if (ck == i) dcov_l = true;
    }
  }
  const bool dcov = __any(dcov_l);
  unsigned long long m0 = __ballot(win[0]);
  unsigned long long m1 = __ballot(win[1]);
  if (l == 0) nbcnt[row] = __popcll(m0) + __popcll(m1) + (dcov ? 0 : 1);

#pragma unroll
  for (int s = 0; s < 2; ++s) {
    int k = s * 64 + l;
    if (k < n && win[s]) {
      int pos = 0;
      for (int j = 0; j < n; ++j)
        if (sW[w][j] && (sE[w][j] & 1023) < myc[s]) ++pos;
      if (!dcov && i < myc[s]) ++pos;
      int e = ((myp[s] >> 10) - 1) & (NEDGE - 1);
      float v = logf(mptr[(size_t)b * NEDGE + e] + 1e-9f);
      if (pos < CAP) {
        nbcol[(size_t)row * CAP + pos] = myc[s];
        nbval[(size_t)row * CAP + pos] = v;
      }
    }
  }
  if (!dcov && l == 0) {   // virtual diagonal (value 0)
    int pos = 0;
    for (int j = 0; j < n; ++j)
      if (sW[w][j] && (sE[w][j] & 1023) < i) ++pos;
    nbcol[(size_t)row * CAP + pos] = i;
    nbval[(size_t)row * CAP + pos] = 0.f;
  }
}

// ---------------- GEMM 64x128 tile, dbuf LDS, ONE barrier + counted vmcnt per K-step ----------------
// loop: barrier -> stage(t+1, buf^1) -> vmcnt(6) [tile t landed] -> compute(t).
// safety: passing barrier(t) proves all waves done reading buf(t-1) == buf(t+1). [dbuf]
// EPI 1: gelu -> bf16 out. EPI 3: plain bf16 out.
template <int EPI>
__global__ __launch_bounds__(256) void gemm_bt(
    const bf16_t* __restrict__ A, const bf16_t* __restrict__ Bw,
    const float* __restrict__ bias, bf16_t* __restrict__ Cb,
    int M, int N, int K) {
  __shared__ bf16_t As[2][64 * 64];    // 16 KB
  __shared__ bf16_t Bs[2][128 * 64];   // 32 KB  (total 48 KB -> 3 blocks/CU)
  const int t = threadIdx.x;
  const int l = t & 63;
  const int w = t >> 6;
  const int wr = w >> 1, wc = w & 1;   // 2x2 waves over 64 rows x 128 cols
  const int bm = blockIdx.y * 64, bn = blockIdx.x * 128;

  f32x4 acc[2][4] = {};

  auto stage = [&](int buf, int k0) {
#pragma unroll
    for (int i = 0; i < 2; ++i) {      // A: 64x64 elems, 2 issues
      int idx = i * 2048 + t * 8;
      int row = idx >> 6, col = idx & 63;
      gload_lds16(A + (size_t)(bm + row) * K + (k0 + col), (void*)(&As[buf][0] + i * 2048 + w * 512));
    }
#pragma unroll
    for (int i = 0; i < 4; ++i) {      // B: 128x64 elems, 4 issues
      int idx = i * 2048 + t * 8;
      int row = idx >> 6, col = idx & 63;
      gload_lds16(Bw + (size_t)(bn + row) * K + (k0 + col), (void*)(&Bs[buf][0] + i * 2048 + w * 512));
    }
  };

  const int nt = K >> 6;
  stage(0, 0);
  for (int kt = 0; kt < nt; ++kt) {
    const int cur = kt & 1;
    __syncthreads();
    if (kt + 1 < nt) {
      stage(cur ^ 1, (kt + 1) << 6);
      asm volatile("s_waitcnt vmcnt(6)" ::: "memory");   // tile kt fully landed
    } else {
      asm volatile("s_waitcnt vmcnt(0)" ::: "memory");
    }
#pragma unroll
    for (int kk = 0; kk < 2; ++kk) {
      bf16x8 af[2], bfr[4];
#pragma unroll
      for (int mi = 0; mi < 2; ++mi)
        af[mi] = *(const bf16x8*)(&As[cur][0] + (wr * 32 + mi * 16 + (l & 15)) * 64 + kk * 32 + (l >> 4) * 8);
#pragma unroll
      for (int ni = 0; ni < 4; ++ni)
        bfr[ni] = *(const bf16x8*)(&Bs[cur][0] + (wc * 64 + ni * 16 + (l & 15)) * 64 + kk * 32 + (l >> 4) * 8);
#pragma unroll
      for (int mi = 0; mi < 2; ++mi)
#pragma unroll
        for (int ni = 0; ni < 4; ++ni)
          acc[mi][ni] = __builtin_amdgcn_mfma_f32_16x16x32_bf16(af[mi], bfr[ni], acc[mi][ni], 0, 0, 0);
    }
  }

  const int r0 = (l >> 4) * 4;   // C/D: row=(lane>>4)*4+reg, col=lane&15
  const int cc = l & 15;
#pragma unroll
  for (int mi = 0; mi < 2; ++mi) {
#pragma unroll
    for (int ni = 0; ni < 4; ++ni) {
      int col = bn + wc * 64 + ni * 16 + cc;
      float bv = bias[col];
#pragma unroll
      for (int r = 0; r < 4; ++r) {
        int row = bm + wr * 32 + mi * 16 + r0 + r;
        float v = acc[mi][ni][r] + bv;
        if (EPI == 1)
          v = 0.5f * v * (1.f + erff(v * 0.70710678118654752f));   // exact GELU
        Cb[(size_t)row * N + col] = (bf16_t)v;
      }
    }
  }
}

// ---------------- fused GEMM(BM=16, BN=256) + bias + bf16-residual + LayerNorm ----------------
// single-barrier + counted-vmcnt K-loop (same proof as gemm_bt).
// FIN=0: y=LN(resid+A@Bw^T+bias) -> bf16 xbout. FIN=1: additionally lnf(y) -> f32 outf (d_out).
template <int FIN>
__global__ __launch_bounds__(256) void gemm_ln(
    const bf16_t* __restrict__ A, const bf16_t* __restrict__ Bw,
    const float* __restrict__ bias, const bf16_t* __restrict__ residb,
    const float* __restrict__ lnw, const float* __restrict__ lnb,
    const float* __restrict__ lnfw, const float* __restrict__ lnfb,
    bf16_t* __restrict__ xbout, float* __restrict__ outf, int K) {
  __shared__ __align__(16) char smem[69632];
  bf16_t* As = (bf16_t*)smem;             // [2][16][64] = 4KB
  bf16_t* Bs = (bf16_t*)(smem + 4096);    // [2][256][64] = 64KB
  float*  E  = (float*)smem;              // epi: [16][258] f32 (aliases, after barrier)
  const int t = threadIdx.x;
  const int l = t & 63;
  const int w = t >> 6;
  const int bm = blockIdx.x * 16;

  f32x4 acc[4] = {};

  auto stage = [&](int buf, int k0) {
    if (w < 2) {   // A tile 16x64: waves 0,1 stage 8 rows each (1 issue)
      int row = w * 8 + (l >> 3), col = (l & 7) * 8;
      gload_lds16(A + (size_t)(bm + row) * K + (k0 + col), (void*)(As + buf * 1024 + w * 512));
    }
#pragma unroll
    for (int i = 0; i < 8; ++i) {   // B tile 256x64: 8 issues per wave
      int rr = (w * 8 + i) * 8 + (l >> 3), col = (l & 7) * 8;
      gload_lds16(Bw + (size_t)rr * K + (k0 + col), (void*)(Bs + buf * 16384 + (w * 8 + i) * 512));
    }
  };

  const int nt = K >> 6;
  stage(0, 0);
  for (int kt = 0; kt < nt; ++kt) {
    const int cur = kt & 1;
    __syncthreads();
    if (kt + 1 < nt) {
      stage(cur ^ 1, (kt + 1) << 6);
      if (w < 2) asm volatile("s_waitcnt vmcnt(9)" ::: "memory");   // 9 from stage(t+1) remain
      else       asm volatile("s_waitcnt vmcnt(8)" ::: "memory");
    } else {
      asm volatile("s_waitcnt vmcnt(0)" ::: "memory");
    }
#pragma unroll
    for (int kk = 0; kk < 2; ++kk) {
      bf16x8 af = *(const bf16x8*)(As + cur * 1024 + (l & 15) * 64 + kk * 32 + (l >> 4) * 8);
#pragma unroll
      for (int ni = 0; ni < 4; ++ni) {
        bf16x8 bfr = *(const bf16x8*)(Bs + cur * 16384 + (w * 64 + ni * 16 + (l & 15)) * 64 + kk * 32 + (l >> 4) * 8);
        acc[ni] = __builtin_amdgcn_mfma_f32_16x16x32_bf16(af, bfr, acc[ni], 0, 0, 0);
      }
    }
  }
  __syncthreads();   // all LDS reads done before E (aliases As/Bs) is written

  // stash C+bias into LDS f32 [16][258]
  const int r0 = (l >> 4) * 4;
  const int cc = l & 15;
#pragma unroll
  for (int ni = 0; ni < 4; ++ni) {
    int col = w * 64 + ni * 16 + cc;
    float bv = bias[col];
#pragma unroll
    for (int r = 0; r < 4; ++r)
      E[(r0 + r) * 258 + col] = acc[ni][r] + bv;
  }
  __syncthreads();

  // LN: 16 threads per row, 16 cols per thread; residual from bf16
  const int row = t >> 4;
  const int sub = t & 15;
  const float* ep = E + row * 258 + sub * 16;
  const bf16_t* rp = residb + (size_t)(bm + row) * 256 + sub * 16;
  float v[16];
  float s = 0.f;
#pragma unroll
  for (int j = 0; j < 4; ++j) {
    float4 a4 = ((const float4*)ep)[j];
    bf16x4 r4 = ((const bf16x4*)rp)[j];
    v[j * 4 + 0] = a4.x + (float)r4[0]; v[j * 4 + 1] = a4.y + (float)r4[1];
    v[j * 4 + 2] = a4.z + (float)r4[2]; v[j * 4 + 3] = a4.w + (float)r4[3];
    s += v[j * 4 + 0] + v[j * 4 + 1] + v[j * 4 + 2] + v[j * 4 + 3];
  }
#pragma unroll
  for (int o = 1; o < 16; o <<= 1) s += __shfl_xor(s, o);
  float mu = s * (1.f / 256.f);
  float e2 = 0.f;
#pragma unroll
  for (int j = 0; j < 16; ++j) { float d = v[j] - mu; e2 += d * d; }
#pragma unroll
  for (int o = 1; o < 16; o <<= 1) e2 += __shfl_xor(e2, o);
  float rs = rsqrtf(e2 * (1.f / 256.f) + 1e-5f);
  float y[16];
#pragma unroll
  for (int j = 0; j < 4; ++j) {
    float4 w4 = ((const float4*)(lnw + sub * 16))[j];
    float4 b4 = ((const float4*)(lnb + sub * 16))[j];
    y[j * 4 + 0] = (v[j * 4 + 0] - mu) * rs * w4.x + b4.x;
    y[j * 4 + 1] = (v[j * 4 + 1] - mu) * rs * w4.y + b4.y;
    y[j * 4 + 2] = (v[j * 4 + 2] - mu) * rs * w4.z + b4.z;
    y[j * 4 + 3] = (v[j * 4 + 3] - mu) * rs * w4.w + b4.w;
  }
  if (FIN == 0) {
    bf16_t* xbo = xbout + (size_t)(bm + row) * 256 + sub * 16;
#pragma unroll
    for (int j = 0; j < 4; ++j) {
      bf16x4 ob;
      ob[0] = (bf16_t)y[j * 4 + 0]; ob[1] = (bf16_t)y[j * 4 + 1];
      ob[2] = (bf16_t)y[j * 4 + 2]; ob[3] = (bf16_t)y[j * 4 + 3];
      ((bf16x4*)xbo)[j] = ob;
    }
  } else {
    // fused final LayerNorm on y
    float s2 = 0.f;
#pragma unroll
    for (int j = 0; j < 16; ++j) s2 += y[j];
#pragma unroll
    for (int o = 1; o < 16; o <<= 1) s2 += __shfl_xor(s2, o);
    float mu2 = s2 * (1.f / 256.f);
    float q2 = 0.f;
#pragma unroll
    for (int j = 0; j < 16; ++j) { float d = y[j] - mu2; q2 += d * d; }
#pragma unroll
    for (int o = 1; o < 16; o <<= 1) q2 += __shfl_xor(q2, o);
    float rs2 = rsqrtf(q2 * (1.f / 256.f) + 1e-5f);
    float* xo = outf + (size_t)(bm + row) * 256 + sub * 16;
#pragma unroll
    for (int j = 0; j < 4; ++j) {
      float4 w4 = ((const float4*)(lnfw + sub * 16))[j];
      float4 b4 = ((const float4*)(lnfb + sub * 16))[j];
      float4 o4 = {(y[j * 4 + 0] - mu2) * rs2 * w4.x + b4.x,
                   (y[j * 4 + 1] - mu2) * rs2 * w4.y + b4.y,
                   (y[j * 4 + 2] - mu2) * rs2 * w4.z + b4.z,
                   (y[j * 4 + 3] - mu2) * rs2 * w4.w + b4.w};
      ((float4*)xo)[j] = o4;
    }
  }
}

// ---------------- sparse attention: XCD-swizzled (batch = bid&7), 4 rows/block ----------------
// qkvb layout: [8192][768] bf16 — q cols 0..255, k 256..511, v 512..767
__global__ __launch_bounds__(256) void k_attn2(
    const bf16_t* __restrict__ qkvb,
    const int* __restrict__ nbcol, const float* __restrict__ nbval,
    const int* __restrict__ nbcnt, bf16_t* __restrict__ aob) {
  const int w = threadIdx.x >> 6;
  const int l = threadIdx.x & 63;
  const int b = blockIdx.x & 7;
  const int row = (b << 10) + (blockIdx.x >> 3) * 4 + w;
  __shared__ float s_s[4][8][97];     // padded: conflict-free ph3
  __shared__ int   s_col[4][CAP];
  __shared__ float s_bias[4][CAP];
  __shared__ float s_den[4][8];
  const int deg = nbcnt[row];
  for (int j = l; j < deg; j += 64) {
    s_col[w][j] = nbcol[(size_t)row * CAP + j];
    s_bias[w][j] = nbval[(size_t)row * CAP + j];
  }
  const int h1 = l & 7;
  float q[32];
  {
    const bf16x8* qp = (const bf16x8*)(qkvb + (size_t)row * 768 + h1 * 32);
#pragma unroll
    for (int u = 0; u < 4; ++u) {
      bf16x8 t8 = qp[u];
#pragma unroll
      for (int j = 0; j < 8; ++j) q[u * 8 + j] = (float)t8[j];
    }
  }
  __syncthreads();

  const float scale = 0.17677669529663687f;   // 1/sqrt(32)
  const int nit = (deg + 7) >> 3;
  float mx = -INFINITY;
  for (int it = 0; it < nit; ++it) {
    int idx = it * 8 + (l >> 3);
    float sc = -INFINITY;
    if (idx < deg) {
      int col = s_col[w][idx];
      const bf16x8* kr = (const bf16x8*)(qkvb + ((size_t)((b << 10) + col)) * 768 + 256 + h1 * 32);
      float d = 0.f;
#pragma unroll
      for (int u = 0; u < 4; ++u) {
        bf16x8 kv = kr[u];
#pragma unroll
        for (int j = 0; j < 8; ++j) d += (float)kv[j] * q[u * 8 + j];
      }
      sc = d * scale + s_bias[w][idx];
      s_s[w][h1][idx] = sc;
    }
    mx = fmaxf(mx, sc);
  }
#pragma unroll
  for (int o = 8; o < 64; o <<= 1) mx = fmaxf(mx, __shfl_xor(mx, o));
  __syncthreads();
  float lsum = 0.f;
  for (int it = 0; it < nit; ++it) {
    int idx = it * 8 + (l >> 3);
    if (idx < deg) {
      float p = __expf(s_s[w][h1][idx] - mx);
      s_s[w][h1][idx] = p;
      lsum += p;
    }
  }
#pragma unroll
  for (int o = 8; o < 64; o <<= 1) lsum += __shfl_xor(lsum, o);
  if (l < 8) s_den[w][l] = lsum;
  __syncthreads();
  const int h3 = l >> 3;
  float a0 = 0.f, a1 = 0.f, a2 = 0.f, a3 = 0.f;
  const bf16_t* vbase = qkvb + ((size_t)(b << 10)) * 768 + 512 + l * 4;
#pragma unroll 4
  for (int idx = 0; idx < deg; ++idx) {
    float p = s_s[w][h3][idx];
    bf16x4 vv = *(const bf16x4*)(vbase + (size_t)s_col[w][idx] * 768);
    a0 += p * (float)vv[0]; a1 += p * (float)vv[1];
    a2 += p * (float)vv[2]; a3 += p * (float)vv[3];
  }
  float rden = 1.f / s_den[w][h3];
  bf16x4 o;
  o[0] = (bf16_t)(a0 * rden); o[1] = (bf16_t)(a1 * rden);
  o[2] = (bf16_t)(a2 * rden); o[3] = (bf16_t)(a3 * rden);
  *(bf16x4*)(aob + (size_t)row * 256 + l * 4) = o;
}

extern "C" void kernel_launch(void* const* d_in, const int* in_sizes, int n_in,
                              void* d_out, int out_size, void* d_ws, size_t ws_size,
                              hipStream_t stream) {
  const float* H    = (const float*)d_in[0];
  const int*   ei   = (const int*)d_in[1];
  const float* m    = (const float*)d_in[2];
  const float* Wqkv = (const float*)d_in[3];
  const float* bqkv = (const float*)d_in[4];
  const float* Wo   = (const float*)d_in[5];
  const float* bo   = (const float*)d_in[6];
  const float* ln1w = (const float*)d_in[7];
  const float* ln1b = (const float*)d_in[8];
  const float* W1   = (const float*)d_in[9];
  const float* b1   = (const float*)d_in[10];
  const float* W2   = (const float*)d_in[11];
  const float* b2   = (const float*)d_in[12];
  const float* ln2w = (const float*)d_in[13];
  const float* ln2b = (const float*)d_in[14];
  const float* lnfw = (const float*)d_in[15];
  const float* lnfb = (const float*)d_in[16];

  char* ws = (char*)d_ws;
  size_t off = 0;
  auto alloc = [&](size_t bytes) {
    void* p = ws + off;
    off += (bytes + 255) & ~(size_t)255;
    return p;
  };

  int*    cnt   = (int*)alloc((size_t)BATCH * NTOK * 4);
  int*    ent   = (int*)alloc((size_t)BATCH * NTOK * CAP * 4);
  int*    nbcol = (int*)alloc((size_t)BATCH * NTOK * CAP * 4);
  float*  nbval = (float*)alloc((size_t)BATCH * NTOK * CAP * 4);
  int*    nbcnt = (int*)alloc((size_t)BATCH * NTOK * 4);
  bf16_t* qkvb  = (bf16_t*)alloc((size_t)8192 * 768 * 2);
  bf16_t* wqkvb = (bf16_t*)alloc((size_t)2 * 768 * 256 * 2);
  bf16_t* wob   = (bf16_t*)alloc((size_t)2 * 256 * 256 * 2);
  bf16_t* w1b   = (bf16_t*)alloc((size_t)2 * 1024 * 256 * 2);
  bf16_t* w2b   = (bf16_t*)alloc((size_t)2 * 256 * 1024 * 2);
  bf16_t* xb    = (bf16_t*)alloc((size_t)8192 * 256 * 2);   // layer input x (bf16)
  bf16_t* x1b   = (bf16_t*)alloc((size_t)8192 * 256 * 2);   // after ln1
  bf16_t* aob   = (bf16_t*)alloc((size_t)8192 * 256 * 2);
  bf16_t* ffb   = (bf16_t*)alloc((size_t)8192 * 1024 * 2);

  k_pre<<<3584, 256, 0, stream>>>((int4*)cnt, H, Wqkv, Wo, W1, W2,
                                  xb, wqkvb, wob, w1b, w2b);
  k_scatter2<<<(BATCH * NEDGE + 255) / 256, 256, 0, stream>>>(ei, cnt, ent);
  k_build2<<<BATCH * NTOK / 4, 256, 0, stream>>>(cnt, ent, m, nbcol, nbval, nbcnt);

  for (int lyr = 0; lyr < 2; ++lyr) {
    gemm_bt<3><<<dim3(768 / 128, 8192 / 64), 256, 0, stream>>>(
        xb, wqkvb + (size_t)lyr * 768 * 256, bqkv + lyr * 768, qkvb, 8192, 768, 256);
    k_attn2<<<BATCH * NTOK / 4, 256, 0, stream>>>(qkvb, nbcol, nbval, nbcnt, aob);
    gemm_ln<0><<<512, 256, 0, stream>>>(
        aob, wob + (size_t)lyr * 256 * 256, bo + lyr * 256, xb,
        ln1w + lyr * 256, ln1b + lyr * 256, nullptr, nullptr, x1b, nullptr, 256);
    gemm_bt<1><<<dim3(1024 / 128, 8192 / 64), 256, 0, stream>>>(
        x1b, w1b + (size_t)lyr * 1024 * 256, b1 + lyr * 1024, ffb, 8192, 1024, 256);
    if (lyr == 0) {
      gemm_ln<0><<<512, 256, 0, stream>>>(
          ffb, w2b + (size_t)lyr * 256 * 1024, b2 + lyr * 256, x1b,
          ln2w + lyr * 256, ln2b + lyr * 256, nullptr, nullptr, xb, nullptr, 1024);
    } else {
      gemm_ln<1><<<512, 256, 0, stream>>>(
          ffb, w2b + (size_t)lyr * 256 * 1024, b2 + lyr * 256, x1b,
          ln2w + lyr * 256, ln2b + lyr * 256, lnfw, lnfb, nullptr, (float*)d_out, 1024);
    }
  }
}

// Round 10
// 197.894 us; speedup vs baseline: 1.1832x; 1.0005x over previous
//
#include <hip/hip_runtime.h>
#include <hip/hip_bf16.h>
#include <math.h>

typedef __bf16 bf16_t;
typedef __attribute__((ext_vector_type(8))) __bf16 bf16x8;
typedef __attribute__((ext_vector_type(4))) __bf16 bf16x4;
typedef __attribute__((ext_vector_type(4))) float f32x4;

#define BATCH 8
#define NTOK 1024
#define NEDGE 16384
#define CAP 96   // max entries per row (deg ~ Poisson(32); P(deg>96) < 1e-20)

// ---------------- async global->LDS (16B per lane, wave-uniform LDS base) ----------------
__device__ __forceinline__ void gload_lds16(const void* g, void* l) {
  __builtin_amdgcn_global_load_lds(
      (const __attribute__((address_space(1))) unsigned int*)(uintptr_t)g,
      (__attribute__((address_space(3))) unsigned int*)(unsigned int)(uintptr_t)l,
      16, 0, 0);
}

// ---------------- fused: f32->bf16 cvt for H + weights; blocks <8 also zero cnt ----------------
__global__ void k_pre(int4* __restrict__ cnt,
                      const float* __restrict__ H, const float* __restrict__ Wqkv,
                      const float* __restrict__ Wo, const float* __restrict__ W1,
                      const float* __restrict__ W2, bf16_t* __restrict__ xb,
                      bf16_t* __restrict__ wqkvb, bf16_t* __restrict__ wob,
                      bf16_t* __restrict__ w1b, bf16_t* __restrict__ w2b) {
  int i = blockIdx.x * 256 + threadIdx.x;   // float4-quad index
  if (blockIdx.x < 8) {
    int4 z = {0, 0, 0, 0};
    cnt[i] = z;                             // 8 blocks x 256 x int4 = 8192 ints
  }
  const float* s; bf16_t* d; int off;
  if (i < 524288)      { s = H;    d = xb;    off = i; }
  else if (i < 622592) { s = Wqkv; d = wqkvb; off = i - 524288; }
  else if (i < 655360) { s = Wo;   d = wob;   off = i - 622592; }
  else if (i < 786432) { s = W1;   d = w1b;   off = i - 655360; }
  else if (i < 917504) { s = W2;   d = w2b;   off = i - 786432; }
  else return;
  float4 v = ((const float4*)s)[off];
  bf16x4 o;
  o[0] = (bf16_t)v.x; o[1] = (bf16_t)v.y; o[2] = (bf16_t)v.z; o[3] = (bf16_t)v.w;
  ((bf16x4*)d)[off] = o;
}

// ---------------- edge scatter: packed (prio<<10|col) appended to per-row lists ----------------
__global__ void k_scatter2(const int* __restrict__ ei, int* __restrict__ cnt,
                           int* __restrict__ ent) {
  int idx = blockIdx.x * 256 + threadIdx.x;
  if (idx >= BATCH * NEDGE) return;
  int b = idx >> 14;
  int e = idx & (NEDGE - 1);
  const int* eb = ei + (size_t)b * 2 * NEDGE;
  int r = eb[e], c = eb[NEDGE + e];
  int rowr = (b << 10) + r, rowc = (b << 10) + c;
  int q = atomicAdd(cnt + rowr, 1);
  if (q < CAP) ent[rowr * CAP + q] = ((e + 1) << 10) | c;
  q = atomicAdd(cnt + rowc, 1);
  if (q < CAP) ent[rowc * CAP + q] = ((NEDGE + e + 1) << 10) | r;
}

// ---------------- CSR build v2: dedup per row in LDS, canonical ascending-col order ----------------
__global__ __launch_bounds__(256) void k_build2(
    const int* __restrict__ cnt, const int* __restrict__ ent,
    const float* __restrict__ mptr,
    int* __restrict__ nbcol, float* __restrict__ nbval, int* __restrict__ nbcnt) {
  const int w = threadIdx.x >> 6;
  const int l = threadIdx.x & 63;
  const int row = blockIdx.x * 4 + w;   // b*1024 + i
  const int i = row & 1023;
  const int b = row >> 10;
  __shared__ int sE[4][CAP];
  __shared__ int sW[4][CAP];
  const int n = min(cnt[row], CAP);
  for (int j = l; j < n; j += 64) sE[w][j] = ent[(size_t)row * CAP + j];
  __syncthreads();

  bool dcov_l = false;
  bool win[2] = {false, false};
  int myc[2], myp[2];
#pragma unroll
  for (int s = 0; s < 2; ++s) {
    int k = s * 64 + l;
    if (k < n) {
      int pk = sE[w][k], ck = pk & 1023;
      myc[s] = ck; myp[s] = pk;
      bool wn = true;
      for (int j = 0; j < n; ++j) {
        int pj = sE[w][j];
        if ((pj & 1023) == ck && pj > pk) wn = false;
      }
      win[s] = wn;
      sW[w][k] = wn ? 1 : 0;
      if (ck == i) dcov_l = true;
    }
  }
  const bool dcov = __any(dcov_l);
  unsigned long long m0 = __ballot(win[0]);
  unsigned long long m1 = __ballot(win[1]);
  if (l == 0) nbcnt[row] = __popcll(m0) + __popcll(m1) + (dcov ? 0 : 1);

#pragma unroll
  for (int s = 0; s < 2; ++s) {
    int k = s * 64 + l;
    if (k < n && win[s]) {
      int pos = 0;
      for (int j = 0; j < n; ++j)
        if (sW[w][j] && (sE[w][j] & 1023) < myc[s]) ++pos;
      if (!dcov && i < myc[s]) ++pos;
      int e = ((myp[s] >> 10) - 1) & (NEDGE - 1);
      float v = logf(mptr[(size_t)b * NEDGE + e] + 1e-9f);
      if (pos < CAP) {
        nbcol[(size_t)row * CAP + pos] = myc[s];
        nbval[(size_t)row * CAP + pos] = v;
      }
    }
  }
  if (!dcov && l == 0) {   // virtual diagonal (value 0)
    int pos = 0;
    for (int j = 0; j < n; ++j)
      if (sW[w][j] && (sE[w][j] & 1023) < i) ++pos;
    nbcol[(size_t)row * CAP + pos] = i;
    nbval[(size_t)row * CAP + pos] = 0.f;
  }
}

// ---------------- GEMM BMx128 tile, dbuf LDS, race-free single-barrier pipeline ----------------
// loop: stage(t+1, buf^1) -> compute(t, buf) -> vmcnt(0) -> barrier.
// barrier certifies: (a) every wave's tile-(t+1) loads landed; (b) all reads of buf done
// before stage(t+2) overwrites it. [canonical minimal 2-phase, learn_hip T3]
// EPI 1: gelu -> bf16 out. EPI 3: plain bf16 out.  BM in {64,128}.
template <int EPI, int BM>
__global__ __launch_bounds__(256) void gemm_bt(
    const bf16_t* __restrict__ A, const bf16_t* __restrict__ Bw,
    const float* __restrict__ bias, bf16_t* __restrict__ Cb,
    int M, int N, int K) {
  constexpr int MI = BM / 32;            // acc rows per wave
  __shared__ bf16_t As[2][BM * 64];
  __shared__ bf16_t Bs[2][128 * 64];
  const int t = threadIdx.x;
  const int l = t & 63;
  const int w = t >> 6;
  const int wr = w >> 1, wc = w & 1;     // 2x2 waves over BM rows x 128 cols
  const int bm = blockIdx.y * BM, bn = blockIdx.x * 128;

  f32x4 acc[MI][4] = {};

  auto stage = [&](int buf, int k0) {
#pragma unroll
    for (int i = 0; i < BM / 32; ++i) {  // A: BM x 64 elems
      int idx = i * 2048 + t * 8;
      int row = idx >> 6, col = idx & 63;
      gload_lds16(A + (size_t)(bm + row) * K + (k0 + col), (void*)(&As[buf][0] + i * 2048 + w * 512));
    }
#pragma unroll
    for (int i = 0; i < 4; ++i) {        // B: 128 x 64 elems
      int idx = i * 2048 + t * 8;
      int row = idx >> 6, col = idx & 63;
      gload_lds16(Bw + (size_t)(bn + row) * K + (k0 + col), (void*)(&Bs[buf][0] + i * 2048 + w * 512));
    }
  };

  const int nt = K >> 6;
  stage(0, 0);
  asm volatile("s_waitcnt vmcnt(0)" ::: "memory");
  __syncthreads();
  for (int kt = 0; kt < nt; ++kt) {
    const int cur = kt & 1;
    if (kt + 1 < nt) stage(cur ^ 1, (kt + 1) << 6);   // loads fly during compute
#pragma unroll
    for (int kk = 0; kk < 2; ++kk) {
      bf16x8 af[MI], bfr[4];
#pragma unroll
      for (int mi = 0; mi < MI; ++mi)
        af[mi] = *(const bf16x8*)(&As[cur][0] + (wr * (BM / 2) + mi * 16 + (l & 15)) * 64 + kk * 32 + (l >> 4) * 8);
#pragma unroll
      for (int ni = 0; ni < 4; ++ni)
        bfr[ni] = *(const bf16x8*)(&Bs[cur][0] + (wc * 64 + ni * 16 + (l & 15)) * 64 + kk * 32 + (l >> 4) * 8);
#pragma unroll
      for (int mi = 0; mi < MI; ++mi)
#pragma unroll
        for (int ni = 0; ni < 4; ++ni)
          acc[mi][ni] = __builtin_amdgcn_mfma_f32_16x16x32_bf16(af[mi], bfr[ni], acc[mi][ni], 0, 0, 0);
    }
    asm volatile("s_waitcnt vmcnt(0)" ::: "memory");
    __syncthreads();
  }

  const int r0 = (l >> 4) * 4;   // C/D: row=(lane>>4)*4+reg, col=lane&15
  const int cc = l & 15;
#pragma unroll
  for (int mi = 0; mi < MI; ++mi) {
#pragma unroll
    for (int ni = 0; ni < 4; ++ni) {
      int col = bn + wc * 64 + ni * 16 + cc;
      float bv = bias[col];
#pragma unroll
      for (int r = 0; r < 4; ++r) {
        int row = bm + wr * (BM / 2) + mi * 16 + r0 + r;
        float v = acc[mi][ni][r] + bv;
        if (EPI == 1)
          v = 0.5f * v * (1.f + erff(v * 0.70710678118654752f));   // exact GELU
        Cb[(size_t)row * N + col] = (bf16_t)v;
      }
    }
  }
}

// ---------------- fused GEMM(BM=16, BN=256) + bias + bf16-residual + LayerNorm ----------------
// same race-free pipeline as gemm_bt.
// FIN=0: y=LN(resid+A@Bw^T+bias) -> bf16 xbout. FIN=1: additionally lnf(y) -> f32 outf (d_out).
template <int FIN>
__global__ __launch_bounds__(256) void gemm_ln(
    const bf16_t* __restrict__ A, const bf16_t* __restrict__ Bw,
    const float* __restrict__ bias, const bf16_t* __restrict__ residb,
    const float* __restrict__ lnw, const float* __restrict__ lnb,
    const float* __restrict__ lnfw, const float* __restrict__ lnfb,
    bf16_t* __restrict__ xbout, float* __restrict__ outf, int K) {
  __shared__ __align__(16) char smem[69632];
  bf16_t* As = (bf16_t*)smem;             // [2][16][64] = 4KB
  bf16_t* Bs = (bf16_t*)(smem + 4096);    // [2][256][64] = 64KB
  float*  E  = (float*)smem;              // epi: [16][258] f32 (aliases, after barrier)
  const int t = threadIdx.x;
  const int l = t & 63;
  const int w = t >> 6;
  const int bm = blockIdx.x * 16;

  f32x4 acc[4] = {};

  auto stage = [&](int buf, int k0) {
    if (w < 2) {   // A tile 16x64: waves 0,1 stage 8 rows each (1 issue)
      int row = w * 8 + (l >> 3), col = (l & 7) * 8;
      gload_lds16(A + (size_t)(bm + row) * K + (k0 + col), (void*)(As + buf * 1024 + w * 512));
    }
#pragma unroll
    for (int i = 0; i < 8; ++i) {   // B tile 256x64: 8 issues per wave
      int rr = (w * 8 + i) * 8 + (l >> 3), col = (l & 7) * 8;
      gload_lds16(Bw + (size_t)rr * K + (k0 + col), (void*)(Bs + buf * 16384 + (w * 8 + i) * 512));
    }
  };

  const int nt = K >> 6;
  stage(0, 0);
  asm volatile("s_waitcnt vmcnt(0)" ::: "memory");
  __syncthreads();
  for (int kt = 0; kt < nt; ++kt) {
    const int cur = kt & 1;
    if (kt + 1 < nt) stage(cur ^ 1, (kt + 1) << 6);
#pragma unroll
    for (int kk = 0; kk < 2; ++kk) {
      bf16x8 af = *(const bf16x8*)(As + cur * 1024 + (l & 15) * 64 + kk * 32 + (l >> 4) * 8);
#pragma unroll
      for (int ni = 0; ni < 4; ++ni) {
        bf16x8 bfr = *(const bf16x8*)(Bs + cur * 16384 + (w * 64 + ni * 16 + (l & 15)) * 64 + kk * 32 + (l >> 4) * 8);
        acc[ni] = __builtin_amdgcn_mfma_f32_16x16x32_bf16(af, bfr, acc[ni], 0, 0, 0);
      }
    }
    asm volatile("s_waitcnt vmcnt(0)" ::: "memory");
    __syncthreads();
  }

  // stash C+bias into LDS f32 [16][258]  (loop-exit barrier certifies all LDS reads done)
  const int r0 = (l >> 4) * 4;
  const int cc = l & 15;
#pragma unroll
  for (int ni = 0; ni < 4; ++ni) {
    int col = w * 64 + ni * 16 + cc;
    float bv = bias[col];
#pragma unroll
    for (int r = 0; r < 4; ++r)
      E[(r0 + r) * 258 + col] = acc[ni][r] + bv;
  }
  __syncthreads();

  // LN: 16 threads per row, 16 cols per thread; residual from bf16
  const int row = t >> 4;
  const int sub = t & 15;
  const float* ep = E + row * 258 + sub * 16;
  const bf16_t* rp = residb + (size_t)(bm + row) * 256 + sub * 16;
  float v[16];
  float s = 0.f;
#pragma unroll
  for (int j = 0; j < 4; ++j) {
    float4 a4 = ((const float4*)ep)[j];
    bf16x4 r4 = ((const bf16x4*)rp)[j];
    v[j * 4 + 0] = a4.x + (float)r4[0]; v[j * 4 + 1] = a4.y + (float)r4[1];
    v[j * 4 + 2] = a4.z + (float)r4[2]; v[j * 4 + 3] = a4.w + (float)r4[3];
    s += v[j * 4 + 0] + v[j * 4 + 1] + v[j * 4 + 2] + v[j * 4 + 3];
  }
#pragma unroll
  for (int o = 1; o < 16; o <<= 1) s += __shfl_xor(s, o);
  float mu = s * (1.f / 256.f);
  float e2 = 0.f;
#pragma unroll
  for (int j = 0; j < 16; ++j) { float d = v[j] - mu; e2 += d * d; }
#pragma unroll
  for (int o = 1; o < 16; o <<= 1) e2 += __shfl_xor(e2, o);
  float rs = rsqrtf(e2 * (1.f / 256.f) + 1e-5f);
  float y[16];
#pragma unroll
  for (int j = 0; j < 4; ++j) {
    float4 w4 = ((const float4*)(lnw + sub * 16))[j];
    float4 b4 = ((const float4*)(lnb + sub * 16))[j];
    y[j * 4 + 0] = (v[j * 4 + 0] - mu) * rs * w4.x + b4.x;
    y[j * 4 + 1] = (v[j * 4 + 1] - mu) * rs * w4.y + b4.y;
    y[j * 4 + 2] = (v[j * 4 + 2] - mu) * rs * w4.z + b4.z;
    y[j * 4 + 3] = (v[j * 4 + 3] - mu) * rs * w4.w + b4.w;
  }
  if (FIN == 0) {
    bf16_t* xbo = xbout + (size_t)(bm + row) * 256 + sub * 16;
#pragma unroll
    for (int j = 0; j < 4; ++j) {
      bf16x4 ob;
      ob[0] = (bf16_t)y[j * 4 + 0]; ob[1] = (bf16_t)y[j * 4 + 1];
      ob[2] = (bf16_t)y[j * 4 + 2]; ob[3] = (bf16_t)y[j * 4 + 3];
      ((bf16x4*)xbo)[j] = ob;
    }
  } else {
    // fused final LayerNorm on y
    float s2 = 0.f;
#pragma unroll
    for (int j = 0; j < 16; ++j) s2 += y[j];
#pragma unroll
    for (int o = 1; o < 16; o <<= 1) s2 += __shfl_xor(s2, o);
    float mu2 = s2 * (1.f / 256.f);
    float q2 = 0.f;
#pragma unroll
    for (int j = 0; j < 16; ++j) { float d = y[j] - mu2; q2 += d * d; }
#pragma unroll
    for (int o = 1; o < 16; o <<= 1) q2 += __shfl_xor(q2, o);
    float rs2 = rsqrtf(q2 * (1.f / 256.f) + 1e-5f);
    float* xo = outf + (size_t)(bm + row) * 256 + sub * 16;
#pragma unroll
    for (int j = 0; j < 4; ++j) {
      float4 w4 = ((const float4*)(lnfw + sub * 16))[j];
      float4 b4 = ((const float4*)(lnfb + sub * 16))[j];
      float4 o4 = {(y[j * 4 + 0] - mu2) * rs2 * w4.x + b4.x,
                   (y[j * 4 + 1] - mu2) * rs2 * w4.y + b4.y,
                   (y[j * 4 + 2] - mu2) * rs2 * w4.z + b4.z,
                   (y[j * 4 + 3] - mu2) * rs2 * w4.w + b4.w};
      ((float4*)xo)[j] = o4;
    }
  }
}

// ---------------- sparse attention: XCD-swizzled (batch = bid&7), 4 rows/block ----------------
// qkvb layout: [8192][768] bf16 — q cols 0..255, k 256..511, v 512..767
__global__ __launch_bounds__(256) void k_attn2(
    const bf16_t* __restrict__ qkvb,
    const int* __restrict__ nbcol, const float* __restrict__ nbval,
    const int* __restrict__ nbcnt, bf16_t* __restrict__ aob) {
  const int w = threadIdx.x >> 6;
  const int l = threadIdx.x & 63;
  const int b = blockIdx.x & 7;
  const int row = (b << 10) + (blockIdx.x >> 3) * 4 + w;
  __shared__ float s_s[4][8][97];     // padded: conflict-free ph3
  __shared__ int   s_col[4][CAP];
  __shared__ float s_bias[4][CAP];
  __shared__ float s_den[4][8];
  const int deg = nbcnt[row];
  for (int j = l; j < deg; j += 64) {
    s_col[w][j] = nbcol[(size_t)row * CAP + j];
    s_bias[w][j] = nbval[(size_t)row * CAP + j];
  }
  const int h1 = l & 7;
  float q[32];
  {
    const bf16x8* qp = (const bf16x8*)(qkvb + (size_t)row * 768 + h1 * 32);
#pragma unroll
    for (int u = 0; u < 4; ++u) {
      bf16x8 t8 = qp[u];
#pragma unroll
      for (int j = 0; j < 8; ++j) q[u * 8 + j] = (float)t8[j];
    }
  }
  __syncthreads();

  const float scale = 0.17677669529663687f;   // 1/sqrt(32)
  const int nit = (deg + 7) >> 3;
  float mx = -INFINITY;
  for (int it = 0; it < nit; ++it) {
    int idx = it * 8 + (l >> 3);
    float sc = -INFINITY;
    if (idx < deg) {
      int col = s_col[w][idx];
      const bf16x8* kr = (const bf16x8*)(qkvb + ((size_t)((b << 10) + col)) * 768 + 256 + h1 * 32);
      float d = 0.f;
#pragma unroll
      for (int u = 0; u < 4; ++u) {
        bf16x8 kv = kr[u];
#pragma unroll
        for (int j = 0; j < 8; ++j) d += (float)kv[j] * q[u * 8 + j];
      }
      sc = d * scale + s_bias[w][idx];
      s_s[w][h1][idx] = sc;
    }
    mx = fmaxf(mx, sc);
  }
#pragma unroll
  for (int o = 8; o < 64; o <<= 1) mx = fmaxf(mx, __shfl_xor(mx, o));
  __syncthreads();
  float lsum = 0.f;
  for (int it = 0; it < nit; ++it) {
    int idx = it * 8 + (l >> 3);
    if (idx < deg) {
      float p = __expf(s_s[w][h1][idx] - mx);
      s_s[w][h1][idx] = p;
      lsum += p;
    }
  }
#pragma unroll
  for (int o = 8; o < 64; o <<= 1) lsum += __shfl_xor(lsum, o);
  if (l < 8) s_den[w][l] = lsum;
  __syncthreads();
  const int h3 = l >> 3;
  float a0 = 0.f, a1 = 0.f, a2 = 0.f, a3 = 0.f;
  const bf16_t* vbase = qkvb + ((size_t)(b << 10)) * 768 + 512 + l * 4;
#pragma unroll 4
  for (int idx = 0; idx < deg; ++idx) {
    float p = s_s[w][h3][idx];
    bf16x4 vv = *(const bf16x4*)(vbase + (size_t)s_col[w][idx] * 768);
    a0 += p * (float)vv[0]; a1 += p * (float)vv[1];
    a2 += p * (float)vv[2]; a3 += p * (float)vv[3];
  }
  float rden = 1.f / s_den[w][h3];
  bf16x4 o;
  o[0] = (bf16_t)(a0 * rden); o[1] = (bf16_t)(a1 * rden);
  o[2] = (bf16_t)(a2 * rden); o[3] = (bf16_t)(a3 * rden);
  *(bf16x4*)(aob + (size_t)row * 256 + l * 4) = o;
}

extern "C" void kernel_launch(void* const* d_in, const int* in_sizes, int n_in,
                              void* d_out, int out_size, void* d_ws, size_t ws_size,
                              hipStream_t stream) {
  const float* H    = (const float*)d_in[0];
  const int*   ei   = (const int*)d_in[1];
  const float* m    = (const float*)d_in[2];
  const float* Wqkv = (const float*)d_in[3];
  const float* bqkv = (const float*)d_in[4];
  const float* Wo   = (const float*)d_in[5];
  const float* bo   = (const float*)d_in[6];
  const float* ln1w = (const float*)d_in[7];
  const float* ln1b = (const float*)d_in[8];
  const float* W1   = (const float*)d_in[9];
  const float* b1   = (const float*)d_in[10];
  const float* W2   = (const float*)d_in[11];
  const float* b2   = (const float*)d_in[12];
  const float* ln2w = (const float*)d_in[13];
  const float* ln2b = (const float*)d_in[14];
  const float* lnfw = (const float*)d_in[15];
  const float* lnfb = (const float*)d_in[16];

  char* ws = (char*)d_ws;
  size_t off = 0;
  auto alloc = [&](size_t bytes) {
    void* p = ws + off;
    off += (bytes + 255) & ~(size_t)255;
    return p;
  };

  int*    cnt   = (int*)alloc((size_t)BATCH * NTOK * 4);
  int*    ent   = (int*)alloc((size_t)BATCH * NTOK * CAP * 4);
  int*    nbcol = (int*)alloc((size_t)BATCH * NTOK * CAP * 4);
  float*  nbval = (float*)alloc((size_t)BATCH * NTOK * CAP * 4);
  int*    nbcnt = (int*)alloc((size_t)BATCH * NTOK * 4);
  bf16_t* qkvb  = (bf16_t*)alloc((size_t)8192 * 768 * 2);
  bf16_t* wqkvb = (bf16_t*)alloc((size_t)2 * 768 * 256 * 2);
  bf16_t* wob   = (bf16_t*)alloc((size_t)2 * 256 * 256 * 2);
  bf16_t* w1b   = (bf16_t*)alloc((size_t)2 * 1024 * 256 * 2);
  bf16_t* w2b   = (bf16_t*)alloc((size_t)2 * 256 * 1024 * 2);
  bf16_t* xb    = (bf16_t*)alloc((size_t)8192 * 256 * 2);   // layer input x (bf16)
  bf16_t* x1b   = (bf16_t*)alloc((size_t)8192 * 256 * 2);   // after ln1
  bf16_t* aob   = (bf16_t*)alloc((size_t)8192 * 256 * 2);
  bf16_t* ffb   = (bf16_t*)alloc((size_t)8192 * 1024 * 2);

  k_pre<<<3584, 256, 0, stream>>>((int4*)cnt, H, Wqkv, Wo, W1, W2,
                                  xb, wqkvb, wob, w1b, w2b);
  k_scatter2<<<(BATCH * NEDGE + 255) / 256, 256, 0, stream>>>(ei, cnt, ent);
  k_build2<<<BATCH * NTOK / 4, 256, 0, stream>>>(cnt, ent, m, nbcol, nbval, nbcnt);

  for (int lyr = 0; lyr < 2; ++lyr) {
    gemm_bt<3, 64><<<dim3(768 / 128, 8192 / 64), 256, 0, stream>>>(
        xb, wqkvb + (size_t)lyr * 768 * 256, bqkv + lyr * 768, qkvb, 8192, 768, 256);
    k_attn2<<<BATCH * NTOK / 4, 256, 0, stream>>>(qkvb, nbcol, nbval, nbcnt, aob);
    gemm_ln<0><<<512, 256, 0, stream>>>(
        aob, wob + (size_t)lyr * 256 * 256, bo + lyr * 256, xb,
        ln1w + lyr * 256, ln1b + lyr * 256, nullptr, nullptr, x1b, nullptr, 256);
    gemm_bt<1, 128><<<dim3(1024 / 128, 8192 / 128), 256, 0, stream>>>(
        x1b, w1b + (size_t)lyr * 1024 * 256, b1 + lyr * 1024, ffb, 8192, 1024, 256);
    if (lyr == 0) {
      gemm_ln<0><<<512, 256, 0, stream>>>(
          ffb, w2b + (size_t)lyr * 256 * 1024, b2 + lyr * 256, x1b,
          ln2w + lyr * 256, ln2b + lyr * 256, nullptr, nullptr, xb, nullptr, 1024);
    } else {
      gemm_ln<1><<<512, 256, 0, stream>>>(
          ffb, w2b + (size_t)lyr * 256 * 1024, b2 + lyr * 256, x1b,
          ln2w + lyr * 256, ln2b + lyr * 256, lnfw, lnfb, nullptr, (float*)d_out, 1024);
    }
  }
}

// Round 11
// 194.836 us; speedup vs baseline: 1.2018x; 1.0157x over previous
//
#include <hip/hip_runtime.h>
#include <hip/hip_bf16.h>
#include <math.h>

typedef __bf16 bf16_t;
typedef __attribute__((ext_vector_type(8))) __bf16 bf16x8;
typedef __attribute__((ext_vector_type(4))) __bf16 bf16x4;
typedef __attribute__((ext_vector_type(4))) float f32x4;

#define BATCH 8
#define NTOK 1024
#define NEDGE 16384
#define CAP 96   // max entries per row (deg ~ Poisson(32); P(deg>96) < 1e-20)

// ---------------- async global->LDS (16B per lane, wave-uniform LDS base) ----------------
__device__ __forceinline__ void gload_lds16(const void* g, void* l) {
  __builtin_amdgcn_global_load_lds(
      (const __attribute__((address_space(1))) unsigned int*)(uintptr_t)g,
      (__attribute__((address_space(3))) unsigned int*)(unsigned int)(uintptr_t)l,
      16, 0, 0);
}

// ---------------- fused: f32->bf16 cvt for H + weights; blocks <8 also zero cnt ----------------
__global__ void k_pre(int4* __restrict__ cnt,
                      const float* __restrict__ H, const float* __restrict__ Wqkv,
                      const float* __restrict__ Wo, const float* __restrict__ W1,
                      const float* __restrict__ W2, bf16_t* __restrict__ xb,
                      bf16_t* __restrict__ wqkvb, bf16_t* __restrict__ wob,
                      bf16_t* __restrict__ w1b, bf16_t* __restrict__ w2b) {
  int i = blockIdx.x * 256 + threadIdx.x;   // float4-quad index
  if (blockIdx.x < 8) {
    int4 z = {0, 0, 0, 0};
    cnt[i] = z;                             // 8 blocks x 256 x int4 = 8192 ints
  }
  const float* s; bf16_t* d; int off;
  if (i < 524288)      { s = H;    d = xb;    off = i; }
  else if (i < 622592) { s = Wqkv; d = wqkvb; off = i - 524288; }
  else if (i < 655360) { s = Wo;   d = wob;   off = i - 622592; }
  else if (i < 786432) { s = W1;   d = w1b;   off = i - 655360; }
  else if (i < 917504) { s = W2;   d = w2b;   off = i - 786432; }
  else return;
  float4 v = ((const float4*)s)[off];
  bf16x4 o;
  o[0] = (bf16_t)v.x; o[1] = (bf16_t)v.y; o[2] = (bf16_t)v.z; o[3] = (bf16_t)v.w;
  ((bf16x4*)d)[off] = o;
}

// ---------------- edge scatter: packed (prio<<10|col) appended to per-row lists ----------------
__global__ void k_scatter2(const int* __restrict__ ei, int* __restrict__ cnt,
                           int* __restrict__ ent) {
  int idx = blockIdx.x * 256 + threadIdx.x;
  if (idx >= BATCH * NEDGE) return;
  int b = idx >> 14;
  int e = idx & (NEDGE - 1);
  const int* eb = ei + (size_t)b * 2 * NEDGE;
  int r = eb[e], c = eb[NEDGE + e];
  int rowr = (b << 10) + r, rowc = (b << 10) + c;
  int q = atomicAdd(cnt + rowr, 1);
  if (q < CAP) ent[rowr * CAP + q] = ((e + 1) << 10) | c;
  q = atomicAdd(cnt + rowc, 1);
  if (q < CAP) ent[rowc * CAP + q] = ((NEDGE + e + 1) << 10) | r;
}

// ---------------- CSR build v2: dedup per row in LDS, canonical ascending-col order ----------------
__global__ __launch_bounds__(256) void k_build2(
    const int* __restrict__ cnt, const int* __restrict__ ent,
    const float* __restrict__ mptr,
    int* __restrict__ nbcol, float* __restrict__ nbval, int* __restrict__ nbcnt) {
  const int w = threadIdx.x >> 6;
  const int l = threadIdx.x & 63;
  const int row = blockIdx.x * 4 + w;   // b*1024 + i
  const int i = row & 1023;
  const int b = row >> 10;
  __shared__ int sE[4][CAP];
  __shared__ int sW[4][CAP];
  const int n = min(cnt[row], CAP);
  for (int j = l; j < n; j += 64) sE[w][j] = ent[(size_t)row * CAP + j];
  __syncthreads();

  bool dcov_l = false;
  bool win[2] = {false, false};
  int myc[2], myp[2];
#pragma unroll
  for (int s = 0; s < 2; ++s) {
    int k = s * 64 + l;
    if (k < n) {
      int pk = sE[w][k], ck = pk & 1023;
      myc[s] = ck; myp[s] = pk;
      bool wn = true;
      for (int j = 0; j < n; ++j) {
        int pj = sE[w][j];
        if ((pj & 1023) == ck && pj > pk) wn = false;
      }
      win[s] = wn;
      sW[w][k] = wn ? 1 : 0;
      if (ck == i) dcov_l = true;
    }
  }
  const bool dcov = __any(dcov_l);
  unsigned long long m0 = __ballot(win[0]);
  unsigned long long m1 = __ballot(win[1]);
  if (l == 0) nbcnt[row] = __popcll(m0) + __popcll(m1) + (dcov ? 0 : 1);

#pragma unroll
  for (int s = 0; s < 2; ++s) {
    int k = s * 64 + l;
    if (k < n && win[s]) {
      int pos = 0;
      for (int j = 0; j < n; ++j)
        if (sW[w][j] && (sE[w][j] & 1023) < myc[s]) ++pos;
      if (!dcov && i < myc[s]) ++pos;
      int e = ((myp[s] >> 10) - 1) & (NEDGE - 1);
      float v = logf(mptr[(size_t)b * NEDGE + e] + 1e-9f);
      if (pos < CAP) {
        nbcol[(size_t)row * CAP + pos] = myc[s];
        nbval[(size_t)row * CAP + pos] = v;
      }
    }
  }
  if (!dcov && l == 0) {   // virtual diagonal (value 0)
    int pos = 0;
    for (int j = 0; j < n; ++j)
      if (sW[w][j] && (sE[w][j] & 1023) < i) ++pos;
    nbcol[(size_t)row * CAP + pos] = i;
    nbval[(size_t)row * CAP + pos] = 0.f;
  }
}

// ---------------- GEMM BMx128 tile, dbuf LDS, race-free single-barrier pipeline ----------------
// loop: stage(t+1, buf^1) -> compute(t, buf) -> vmcnt(0) -> barrier.
// EPI 1: gelu -> bf16 out. EPI 3: plain bf16 out.  BM in {64,128}.
template <int EPI, int BM>
__global__ __launch_bounds__(256) void gemm_bt(
    const bf16_t* __restrict__ A, const bf16_t* __restrict__ Bw,
    const float* __restrict__ bias, bf16_t* __restrict__ Cb,
    int M, int N, int K) {
  constexpr int MI = BM / 32;            // acc rows per wave
  __shared__ bf16_t As[2][BM * 64];
  __shared__ bf16_t Bs[2][128 * 64];
  const int t = threadIdx.x;
  const int l = t & 63;
  const int w = t >> 6;
  const int wr = w >> 1, wc = w & 1;     // 2x2 waves over BM rows x 128 cols
  const int bm = blockIdx.y * BM, bn = blockIdx.x * 128;

  f32x4 acc[MI][4] = {};

  auto stage = [&](int buf, int k0) {
#pragma unroll
    for (int i = 0; i < BM / 32; ++i) {  // A: BM x 64 elems
      int idx = i * 2048 + t * 8;
      int row = idx >> 6, col = idx & 63;
      gload_lds16(A + (size_t)(bm + row) * K + (k0 + col), (void*)(&As[buf][0] + i * 2048 + w * 512));
    }
#pragma unroll
    for (int i = 0; i < 4; ++i) {        // B: 128 x 64 elems
      int idx = i * 2048 + t * 8;
      int row = idx >> 6, col = idx & 63;
      gload_lds16(Bw + (size_t)(bn + row) * K + (k0 + col), (void*)(&Bs[buf][0] + i * 2048 + w * 512));
    }
  };

  const int nt = K >> 6;
  stage(0, 0);
  asm volatile("s_waitcnt vmcnt(0)" ::: "memory");
  __syncthreads();
  for (int kt = 0; kt < nt; ++kt) {
    const int cur = kt & 1;
    if (kt + 1 < nt) stage(cur ^ 1, (kt + 1) << 6);   // loads fly during compute
#pragma unroll
    for (int kk = 0; kk < 2; ++kk) {
      bf16x8 af[MI], bfr[4];
#pragma unroll
      for (int mi = 0; mi < MI; ++mi)
        af[mi] = *(const bf16x8*)(&As[cur][0] + (wr * (BM / 2) + mi * 16 + (l & 15)) * 64 + kk * 32 + (l >> 4) * 8);
#pragma unroll
      for (int ni = 0; ni < 4; ++ni)
        bfr[ni] = *(const bf16x8*)(&Bs[cur][0] + (wc * 64 + ni * 16 + (l & 15)) * 64 + kk * 32 + (l >> 4) * 8);
#pragma unroll
      for (int mi = 0; mi < MI; ++mi)
#pragma unroll
        for (int ni = 0; ni < 4; ++ni)
          acc[mi][ni] = __builtin_amdgcn_mfma_f32_16x16x32_bf16(af[mi], bfr[ni], acc[mi][ni], 0, 0, 0);
    }
    asm volatile("s_waitcnt vmcnt(0)" ::: "memory");
    __syncthreads();
  }

  const int r0 = (l >> 4) * 4;   // C/D: row=(lane>>4)*4+reg, col=lane&15
  const int cc = l & 15;
#pragma unroll
  for (int mi = 0; mi < MI; ++mi) {
#pragma unroll
    for (int ni = 0; ni < 4; ++ni) {
      int col = bn + wc * 64 + ni * 16 + cc;
      float bv = bias[col];
#pragma unroll
      for (int r = 0; r < 4; ++r) {
        int row = bm + wr * (BM / 2) + mi * 16 + r0 + r;
        float v = acc[mi][ni][r] + bv;
        if (EPI == 1)
          v = 0.5f * v * (1.f + erff(v * 0.70710678118654752f));   // exact GELU
        Cb[(size_t)row * N + col] = (bf16_t)v;
      }
    }
  }
}

// ---------------- fused attention + out-projection + residual + LN1 ----------------
// grid 512 (XCD-swizzled: batch = bid&7), block = 16 rows. Wave w: rows bm+w*4..+3 serial.
// attn out -> LDS ao[16][264] bf16 -> MFMA A-operand for oproj (Wo staged via gload_lds;
// k-tile 0 prestaged BEFORE attention so its latency hides under the attn phase).
__global__ __launch_bounds__(256) void k_attn_oproj(
    const bf16_t* __restrict__ qkvb,
    const int* __restrict__ nbcol, const float* __restrict__ nbval,
    const int* __restrict__ nbcnt,
    const bf16_t* __restrict__ Wo, const float* __restrict__ bo,
    const bf16_t* __restrict__ residb,
    const float* __restrict__ lnw, const float* __restrict__ lnb,
    bf16_t* __restrict__ xbout) {
  __shared__ __align__(16) char smem[57856];
  bf16_t* Bs    = (bf16_t*)smem;             // [256][64] single-buffer k-tile (32 KB)
  bf16_t* ao    = (bf16_t*)(smem + 32768);   // [16][264] attn out (8448 B; stride 264 -> 2-way-free frags)
  float*  s_s   = (float*)(smem + 41216);    // [4][8][97] scores (12416 B)
  int*    s_col = (int*)(smem + 53632);      // [4][96]
  float*  s_bia = (float*)(smem + 55168);    // [4][96]
  float*  E     = (float*)(smem + 41216);    // [16][258] f32, aliases attn buffers (dead)
  const int t = threadIdx.x, l = t & 63, w = t >> 6;
  const int b = blockIdx.x & 7;              // XCD-swizzle: one batch per XCD
  const int bm = (b << 10) + (blockIdx.x >> 3) * 16;

  auto stageB = [&](int k0) {
#pragma unroll
    for (int i = 0; i < 8; ++i) {
      int rr = (w * 8 + i) * 8 + (l >> 3), col = (l & 7) * 8;
      gload_lds16(Wo + (size_t)rr * 256 + (k0 + col), (void*)(Bs + (w * 8 + i) * 512));
    }
  };
  stageB(0);   // W_o tile 0 flies during the whole attention phase

  // ---------------- attention (per-wave; in-wave LDS fences, shfl for denom) ----------------
  const float scale = 0.17677669529663687f;   // 1/sqrt(32)
  const int h1 = l & 7;
  for (int rr = 0; rr < 4; ++rr) {
    const int row = bm + w * 4 + rr;
    const int deg = nbcnt[row];
    asm volatile("s_waitcnt lgkmcnt(0)" ::: "memory");   // prev iter's LDS reads ordered
    for (int j = l; j < deg; j += 64) {
      s_col[w * 96 + j] = nbcol[(size_t)row * CAP + j];
      s_bia[w * 96 + j] = nbval[(size_t)row * CAP + j];
    }
    float q[32];
    {
      const bf16x8* qp = (const bf16x8*)(qkvb + (size_t)row * 768 + h1 * 32);
#pragma unroll
      for (int u = 0; u < 4; ++u) {
        bf16x8 t8 = qp[u];
#pragma unroll
        for (int j = 0; j < 8; ++j) q[u * 8 + j] = (float)t8[j];
      }
    }
    asm volatile("s_waitcnt lgkmcnt(0)" ::: "memory");   // s_col/s_bia visible wave-wide

    const int nit = (deg + 7) >> 3;
    float mx = -INFINITY;
    for (int it = 0; it < nit; ++it) {
      int idx = it * 8 + (l >> 3);
      float sc = -INFINITY;
      if (idx < deg) {
        int col = s_col[w * 96 + idx];
        const bf16x8* kr = (const bf16x8*)(qkvb + ((size_t)((b << 10) + col)) * 768 + 256 + h1 * 32);
        float d = 0.f;
#pragma unroll
        for (int u = 0; u < 4; ++u) {
          bf16x8 kv = kr[u];
#pragma unroll
          for (int j = 0; j < 8; ++j) d += (float)kv[j] * q[u * 8 + j];
        }
        sc = d * scale + s_bia[w * 96 + idx];
        s_s[(w * 8 + h1) * 97 + idx] = sc;
      }
      mx = fmaxf(mx, sc);
    }
#pragma unroll
    for (int o = 8; o < 64; o <<= 1) mx = fmaxf(mx, __shfl_xor(mx, o));
    asm volatile("s_waitcnt lgkmcnt(0)" ::: "memory");
    float lsum = 0.f;
    for (int it = 0; it < nit; ++it) {
      int idx = it * 8 + (l >> 3);
      if (idx < deg) {
        float p = __expf(s_s[(w * 8 + h1) * 97 + idx] - mx);
        s_s[(w * 8 + h1) * 97 + idx] = p;
        lsum += p;
      }
    }
#pragma unroll
    for (int o = 8; o < 64; o <<= 1) lsum += __shfl_xor(lsum, o);
    const int h3 = l >> 3;
    float den = __shfl(lsum, h3);             // lane h3 holds head-h3 denom
    asm volatile("s_waitcnt lgkmcnt(0)" ::: "memory");
    float a0 = 0.f, a1 = 0.f, a2 = 0.f, a3 = 0.f;
    const bf16_t* vbase = qkvb + ((size_t)(b << 10)) * 768 + 512 + l * 4;
#pragma unroll 4
    for (int idx = 0; idx < deg; ++idx) {
      float p = s_s[(w * 8 + h3) * 97 + idx];
      bf16x4 vv = *(const bf16x4*)(vbase + (size_t)s_col[w * 96 + idx] * 768);
      a0 += p * (float)vv[0]; a1 += p * (float)vv[1];
      a2 += p * (float)vv[2]; a3 += p * (float)vv[3];
    }
    float rden = 1.f / den;
    bf16x4 o4;
    o4[0] = (bf16_t)(a0 * rden); o4[1] = (bf16_t)(a1 * rden);
    o4[2] = (bf16_t)(a2 * rden); o4[3] = (bf16_t)(a3 * rden);
    *(bf16x4*)(ao + (w * 4 + rr) * 264 + l * 4) = o4;
  }
  asm volatile("s_waitcnt vmcnt(0) lgkmcnt(0)" ::: "memory");   // ao written; Bs tile 0 landed
  __syncthreads();

  // ---------------- out-projection: C[16][256] = ao @ Wo^T, K=256 in 4 tiles ----------------
  f32x4 acc[4] = {};
  for (int kt = 0; kt < 4; ++kt) {
#pragma unroll
    for (int kk = 0; kk < 2; ++kk) {
      bf16x8 af = *(const bf16x8*)(ao + (l & 15) * 264 + kt * 64 + kk * 32 + (l >> 4) * 8);
#pragma unroll
      for (int ni = 0; ni < 4; ++ni) {
        bf16x8 bfr = *(const bf16x8*)(Bs + (w * 64 + ni * 16 + (l & 15)) * 64 + kk * 32 + (l >> 4) * 8);
        acc[ni] = __builtin_amdgcn_mfma_f32_16x16x32_bf16(af, bfr, acc[ni], 0, 0, 0);
      }
    }
    __syncthreads();                       // all Bs reads done
    if (kt < 3) {
      stageB((kt + 1) * 64);
      asm volatile("s_waitcnt vmcnt(0)" ::: "memory");
      __syncthreads();                     // next tile ready for all waves
    }
  }

  // E write (E doesn't alias ao/Bs -> no barrier needed before)
  const int r0 = (l >> 4) * 4;
  const int cc = l & 15;
#pragma unroll
  for (int ni = 0; ni < 4; ++ni) {
    int col = w * 64 + ni * 16 + cc;
    float bv = bo[col];
#pragma unroll
    for (int r = 0; r < 4; ++r)
      E[(r0 + r) * 258 + col] = acc[ni][r] + bv;
  }
  __syncthreads();

  // residual + LN: 16 threads/row
  const int row = t >> 4;
  const int sub = t & 15;
  const float* ep = E + row * 258 + sub * 16;
  const bf16_t* rp = residb + (size_t)(bm + row) * 256 + sub * 16;
  float v[16];
  float s = 0.f;
#pragma unroll
  for (int j = 0; j < 4; ++j) {
    float4 a4 = ((const float4*)ep)[j];
    bf16x4 r4 = ((const bf16x4*)rp)[j];
    v[j * 4 + 0] = a4.x + (float)r4[0]; v[j * 4 + 1] = a4.y + (float)r4[1];
    v[j * 4 + 2] = a4.z + (float)r4[2]; v[j * 4 + 3] = a4.w + (float)r4[3];
    s += v[j * 4 + 0] + v[j * 4 + 1] + v[j * 4 + 2] + v[j * 4 + 3];
  }
#pragma unroll
  for (int o = 1; o < 16; o <<= 1) s += __shfl_xor(s, o);
  float mu = s * (1.f / 256.f);
  float e2 = 0.f;
#pragma unroll
  for (int j = 0; j < 16; ++j) { float d = v[j] - mu; e2 += d * d; }
#pragma unroll
  for (int o = 1; o < 16; o <<= 1) e2 += __shfl_xor(e2, o);
  float rs = rsqrtf(e2 * (1.f / 256.f) + 1e-5f);
  bf16_t* xbo = xbout + (size_t)(bm + row) * 256 + sub * 16;
#pragma unroll
  for (int j = 0; j < 4; ++j) {
    float4 w4 = ((const float4*)(lnw + sub * 16))[j];
    float4 b4 = ((const float4*)(lnb + sub * 16))[j];
    bf16x4 ob;
    ob[0] = (bf16_t)((v[j * 4 + 0] - mu) * rs * w4.x + b4.x);
    ob[1] = (bf16_t)((v[j * 4 + 1] - mu) * rs * w4.y + b4.y);
    ob[2] = (bf16_t)((v[j * 4 + 2] - mu) * rs * w4.z + b4.z);
    ob[3] = (bf16_t)((v[j * 4 + 3] - mu) * rs * w4.w + b4.w);
    ((bf16x4*)xbo)[j] = ob;
  }
}

// ---------------- fused GEMM(BM=16, BN=256) + bias + bf16-residual + LayerNorm ----------------
// race-free pipeline. FIN=0: bf16 xbout. FIN=1: additionally lnf(y) -> f32 outf (d_out).
template <int FIN>
__global__ __launch_bounds__(256) void gemm_ln(
    const bf16_t* __restrict__ A, const bf16_t* __restrict__ Bw,
    const float* __restrict__ bias, const bf16_t* __restrict__ residb,
    const float* __restrict__ lnw, const float* __restrict__ lnb,
    const float* __restrict__ lnfw, const float* __restrict__ lnfb,
    bf16_t* __restrict__ xbout, float* __restrict__ outf, int K) {
  __shared__ __align__(16) char smem[69632];
  bf16_t* As = (bf16_t*)smem;             // [2][16][64] = 4KB
  bf16_t* Bs = (bf16_t*)(smem + 4096);    // [2][256][64] = 64KB
  float*  E  = (float*)smem;              // epi: [16][258] f32 (aliases, after barrier)
  const int t = threadIdx.x;
  const int l = t & 63;
  const int w = t >> 6;
  const int bm = blockIdx.x * 16;

  f32x4 acc[4] = {};

  auto stage = [&](int buf, int k0) {
    if (w < 2) {
      int row = w * 8 + (l >> 3), col = (l & 7) * 8;
      gload_lds16(A + (size_t)(bm + row) * K + (k0 + col), (void*)(As + buf * 1024 + w * 512));
    }
#pragma unroll
    for (int i = 0; i < 8; ++i) {
      int rr = (w * 8 + i) * 8 + (l >> 3), col = (l & 7) * 8;
      gload_lds16(Bw + (size_t)rr * K + (k0 + col), (void*)(Bs + buf * 16384 + (w * 8 + i) * 512));
    }
  };

  const int nt = K >> 6;
  stage(0, 0);
  asm volatile("s_waitcnt vmcnt(0)" ::: "memory");
  __syncthreads();
  for (int kt = 0; kt < nt; ++kt) {
    const int cur = kt & 1;
    if (kt + 1 < nt) stage(cur ^ 1, (kt + 1) << 6);
#pragma unroll
    for (int kk = 0; kk < 2; ++kk) {
      bf16x8 af = *(const bf16x8*)(As + cur * 1024 + (l & 15) * 64 + kk * 32 + (l >> 4) * 8);
#pragma unroll
      for (int ni = 0; ni < 4; ++ni) {
        bf16x8 bfr = *(const bf16x8*)(Bs + cur * 16384 + (w * 64 + ni * 16 + (l & 15)) * 64 + kk * 32 + (l >> 4) * 8);
        acc[ni] = __builtin_amdgcn_mfma_f32_16x16x32_bf16(af, bfr, acc[ni], 0, 0, 0);
      }
    }
    asm volatile("s_waitcnt vmcnt(0)" ::: "memory");
    __syncthreads();
  }

  const int r0 = (l >> 4) * 4;
  const int cc = l & 15;
#pragma unroll
  for (int ni = 0; ni < 4; ++ni) {
    int col = w * 64 + ni * 16 + cc;
    float bv = bias[col];
#pragma unroll
    for (int r = 0; r < 4; ++r)
      E[(r0 + r) * 258 + col] = acc[ni][r] + bv;
  }
  __syncthreads();

  const int row = t >> 4;
  const int sub = t & 15;
  const float* ep = E + row * 258 + sub * 16;
  const bf16_t* rp = residb + (size_t)(bm + row) * 256 + sub * 16;
  float v[16];
  float s = 0.f;
#pragma unroll
  for (int j = 0; j < 4; ++j) {
    float4 a4 = ((const float4*)ep)[j];
    bf16x4 r4 = ((const bf16x4*)rp)[j];
    v[j * 4 + 0] = a4.x + (float)r4[0]; v[j * 4 + 1] = a4.y + (float)r4[1];
    v[j * 4 + 2] = a4.z + (float)r4[2]; v[j * 4 + 3] = a4.w + (float)r4[3];
    s += v[j * 4 + 0] + v[j * 4 + 1] + v[j * 4 + 2] + v[j * 4 + 3];
  }
#pragma unroll
  for (int o = 1; o < 16; o <<= 1) s += __shfl_xor(s, o);
  float mu = s * (1.f / 256.f);
  float e2 = 0.f;
#pragma unroll
  for (int j = 0; j < 16; ++j) { float d = v[j] - mu; e2 += d * d; }
#pragma unroll
  for (int o = 1; o < 16; o <<= 1) e2 += __shfl_xor(e2, o);
  float rs = rsqrtf(e2 * (1.f / 256.f) + 1e-5f);
  float y[16];
#pragma unroll
  for (int j = 0; j < 4; ++j) {
    float4 w4 = ((const float4*)(lnw + sub * 16))[j];
    float4 b4 = ((const float4*)(lnb + sub * 16))[j];
    y[j * 4 + 0] = (v[j * 4 + 0] - mu) * rs * w4.x + b4.x;
    y[j * 4 + 1] = (v[j * 4 + 1] - mu) * rs * w4.y + b4.y;
    y[j * 4 + 2] = (v[j * 4 + 2] - mu) * rs * w4.z + b4.z;
    y[j * 4 + 3] = (v[j * 4 + 3] - mu) * rs * w4.w + b4.w;
  }
  if (FIN == 0) {
    bf16_t* xbo = xbout + (size_t)(bm + row) * 256 + sub * 16;
#pragma unroll
    for (int j = 0; j < 4; ++j) {
      bf16x4 ob;
      ob[0] = (bf16_t)y[j * 4 + 0]; ob[1] = (bf16_t)y[j * 4 + 1];
      ob[2] = (bf16_t)y[j * 4 + 2]; ob[3] = (bf16_t)y[j * 4 + 3];
      ((bf16x4*)xbo)[j] = ob;
    }
  } else {
    float s2 = 0.f;
#pragma unroll
    for (int j = 0; j < 16; ++j) s2 += y[j];
#pragma unroll
    for (int o = 1; o < 16; o <<= 1) s2 += __shfl_xor(s2, o);
    float mu2 = s2 * (1.f / 256.f);
    float q2 = 0.f;
#pragma unroll
    for (int j = 0; j < 16; ++j) { float d = y[j] - mu2; q2 += d * d; }
#pragma unroll
    for (int o = 1; o < 16; o <<= 1) q2 += __shfl_xor(q2, o);
    float rs2 = rsqrtf(q2 * (1.f / 256.f) + 1e-5f);
    float* xo = outf + (size_t)(bm + row) * 256 + sub * 16;
#pragma unroll
    for (int j = 0; j < 4; ++j) {
      float4 w4 = ((const float4*)(lnfw + sub * 16))[j];
      float4 b4 = ((const float4*)(lnfb + sub * 16))[j];
      float4 o4 = {(y[j * 4 + 0] - mu2) * rs2 * w4.x + b4.x,
                   (y[j * 4 + 1] - mu2) * rs2 * w4.y + b4.y,
                   (y[j * 4 + 2] - mu2) * rs2 * w4.z + b4.z,
                   (y[j * 4 + 3] - mu2) * rs2 * w4.w + b4.w};
      ((float4*)xo)[j] = o4;
    }
  }
}

extern "C" void kernel_launch(void* const* d_in, const int* in_sizes, int n_in,
                              void* d_out, int out_size, void* d_ws, size_t ws_size,
                              hipStream_t stream) {
  const float* H    = (const float*)d_in[0];
  const int*   ei   = (const int*)d_in[1];
  const float* m    = (const float*)d_in[2];
  const float* Wqkv = (const float*)d_in[3];
  const float* bqkv = (const float*)d_in[4];
  const float* Wo   = (const float*)d_in[5];
  const float* bo   = (const float*)d_in[6];
  const float* ln1w = (const float*)d_in[7];
  const float* ln1b = (const float*)d_in[8];
  const float* W1   = (const float*)d_in[9];
  const float* b1   = (const float*)d_in[10];
  const float* W2   = (const float*)d_in[11];
  const float* b2   = (const float*)d_in[12];
  const float* ln2w = (const float*)d_in[13];
  const float* ln2b = (const float*)d_in[14];
  const float* lnfw = (const float*)d_in[15];
  const float* lnfb = (const float*)d_in[16];

  char* ws = (char*)d_ws;
  size_t off = 0;
  auto alloc = [&](size_t bytes) {
    void* p = ws + off;
    off += (bytes + 255) & ~(size_t)255;
    return p;
  };

  int*    cnt   = (int*)alloc((size_t)BATCH * NTOK * 4);
  int*    ent   = (int*)alloc((size_t)BATCH * NTOK * CAP * 4);
  int*    nbcol = (int*)alloc((size_t)BATCH * NTOK * CAP * 4);
  float*  nbval = (float*)alloc((size_t)BATCH * NTOK * CAP * 4);
  int*    nbcnt = (int*)alloc((size_t)BATCH * NTOK * 4);
  bf16_t* qkvb  = (bf16_t*)alloc((size_t)8192 * 768 * 2);
  bf16_t* wqkvb = (bf16_t*)alloc((size_t)2 * 768 * 256 * 2);
  bf16_t* wob   = (bf16_t*)alloc((size_t)2 * 256 * 256 * 2);
  bf16_t* w1b   = (bf16_t*)alloc((size_t)2 * 1024 * 256 * 2);
  bf16_t* w2b   = (bf16_t*)alloc((size_t)2 * 256 * 1024 * 2);
  bf16_t* xb    = (bf16_t*)alloc((size_t)8192 * 256 * 2);   // layer input x (bf16)
  bf16_t* x1b   = (bf16_t*)alloc((size_t)8192 * 256 * 2);   // after ln1
  bf16_t* ffb   = (bf16_t*)alloc((size_t)8192 * 1024 * 2);

  k_pre<<<3584, 256, 0, stream>>>((int4*)cnt, H, Wqkv, Wo, W1, W2,
                                  xb, wqkvb, wob, w1b, w2b);
  k_scatter2<<<(BATCH * NEDGE + 255) / 256, 256, 0, stream>>>(ei, cnt, ent);
  k_build2<<<BATCH * NTOK / 4, 256, 0, stream>>>(cnt, ent, m, nbcol, nbval, nbcnt);

  for (int lyr = 0; lyr < 2; ++lyr) {
    gemm_bt<3, 64><<<dim3(768 / 128, 8192 / 64), 256, 0, stream>>>(
        xb, wqkvb + (size_t)lyr * 768 * 256, bqkv + lyr * 768, qkvb, 8192, 768, 256);
    k_attn_oproj<<<512, 256, 0, stream>>>(
        qkvb, nbcol, nbval, nbcnt,
        wob + (size_t)lyr * 256 * 256, bo + lyr * 256, xb,
        ln1w + lyr * 256, ln1b + lyr * 256, x1b);
    gemm_bt<1, 128><<<dim3(1024 / 128, 8192 / 128), 256, 0, stream>>>(
        x1b, w1b + (size_t)lyr * 1024 * 256, b1 + lyr * 1024, ffb, 8192, 1024, 256);
    if (lyr == 0) {
      gemm_ln<0><<<512, 256, 0, stream>>>(
          ffb, w2b + (size_t)lyr * 256 * 1024, b2 + lyr * 256, x1b,
          ln2w + lyr * 256, ln2b + lyr * 256, nullptr, nullptr, xb, nullptr, 1024);
    } else {
      gemm_ln<1><<<512, 256, 0, stream>>>(
          ffb, w2b + (size_t)lyr * 256 * 1024, b2 + lyr * 256, x1b,
          ln2w + lyr * 256, ln2b + lyr * 256, lnfw, lnfb, nullptr, (float*)d_out, 1024);
    }
  }
}